// Round 4
// baseline (1154.159 us; speedup 1.0000x reference)
//
#include <hip/hip_runtime.h>
#include <cstdint>
#include <cstddef>

#define F_IN  128
#define F_HID 64
#define F_OUT 40

#define BSH   9     // bucket = dst >> 9 (512 nodes/bucket)
#define NBMAX 256   // supports N <= 131072
#define CHUNK 4096  // edges per partition block

#define BLD_T   512   // build_k threads
#define BLD_CAP 10240 // LDS-staged edges per bucket (40 KB)

typedef __attribute__((ext_vector_type(8))) short short8;   // 8 bf16 = 4 VGPR
typedef __attribute__((ext_vector_type(4))) float f32x4;    // MFMA C/D

// bf16 <-> f32 helpers (RNE on pack; values are finite)
__device__ __forceinline__ unsigned short f2bf(float f) {
  unsigned u = __float_as_uint(f);
  u += 0x7fffu + ((u >> 16) & 1u);
  return (unsigned short)(u >> 16);
}
__device__ __forceinline__ float bf2f(unsigned short b) {
  return __uint_as_float((unsigned)b << 16);
}
__device__ __forceinline__ float bflo(unsigned u) { return __uint_as_float(u << 16); }
__device__ __forceinline__ float bfhi(unsigned u) { return __uint_as_float(u & 0xffff0000u); }
__device__ __forceinline__ unsigned packbf(float lo, float hi) {
  return (unsigned)f2bf(lo) | ((unsigned)f2bf(hi) << 16);
}

// ---------------------------------------------------------------------------
// FRONT (fused): blocks [0,NBLK) run pcount (block 0 additionally emits the
// w2s MFMA-swizzled copy of W2); blocks [NBLK,+gemmBlks) run MFMA GEMM1,
// each converting W1 into a 16 KB LDS B-fragment copy first.
// B-frag (16x16x32): lane holds B^T[n=lane&15][k=(lane>>4)*8+j], j=0..7.
// ---------------------------------------------------------------------------
__global__ __launch_bounds__(256) void front_k(const float* __restrict__ x,
                                               const float* __restrict__ W1,
                                               const float* __restrict__ W2,
                                               unsigned short* __restrict__ w2s,
                                               unsigned short* __restrict__ xw, int N,
                                               const int* __restrict__ ei,
                                               int* __restrict__ counts,
                                               int E, int NBLK, int NBUCK) {
  __shared__ int lh[NBMAX];
  __shared__ unsigned short w1l[8192];    // 16 KB swizzled W1 (gemm1 branch)
  int t = threadIdx.x;

  if ((int)blockIdx.x < NBLK) {
    // ---- pcount ----
    int blk = blockIdx.x;
    lh[t] = 0;
    __syncthreads();
    int e0 = blk * CHUNK;
    int n = min(CHUNK, E - e0);
    for (int i = t; i < n; i += 256)
      atomicAdd(&lh[((unsigned)ei[E + e0 + i]) >> BSH], 1);
    __syncthreads();
    if (t < NBUCK) counts[t * NBLK + blk] = lh[t];
    if (blk == 0) {
      // emit swizzled W2 (cols >= 40 zero) for GEMM2
      for (int i = t; i < 3072; i += 256) {
        int f = i >> 9, r = i & 511;
        int lane = r >> 3, jj = r & 7;
        int ct = f >> 1, ks = f & 1;
        int n2 = ct * 16 + (lane & 15);
        int k = ks * 32 + (lane >> 4) * 8 + jj;
        w2s[i] = (n2 < F_OUT) ? f2bf(W2[k * F_OUT + n2]) : (unsigned short)0;
      }
    }
    return;
  }

  // ---- gemm1: convert W1 -> LDS (all threads, coalesced global reads) ----
  {
    int k = t >> 1, n0 = (t & 1) * 32;       // thread owns W1[k][n0..n0+32)
    const float4* wp = (const float4*)(W1 + k * F_HID + n0);
    float4 v[8];
#pragma unroll
    for (int u = 0; u < 8; ++u) v[u] = wp[u];
#pragma unroll
    for (int u = 0; u < 32; ++u) {
      int n = n0 + u;
      float f = ((const float*)v)[u];
      int idx = ((n >> 4) * 4 + (k >> 5)) * 512 +
                (((k >> 3) & 3) * 16 + (n & 15)) * 8 + (k & 7);
      w1l[idx] = f2bf(f);
    }
  }
  __syncthreads();

  int gblk = blockIdx.x - NBLK;
  int lane = t & 63;
  int wid  = gblk * 4 + (t >> 6);
  int row0 = wid * 16;
  if (row0 >= N) return;
  int m = lane & 15, q = lane >> 4;

  if (row0 + 16 <= N) {
    short8 b[16];
#pragma unroll
    for (int f = 0; f < 16; ++f)
      b[f] = *(const short8*)(w1l + f * 512 + lane * 8);

    short8 a[4];
#pragma unroll
    for (int ks = 0; ks < 4; ++ks) {
      const float* xp = x + (size_t)(row0 + m) * F_IN + ks * 32 + q * 8;
      float4 v0 = *(const float4*)xp;
      float4 v1 = *(const float4*)(xp + 4);
      short8 tt;
      tt[0] = (short)f2bf(v0.x); tt[1] = (short)f2bf(v0.y);
      tt[2] = (short)f2bf(v0.z); tt[3] = (short)f2bf(v0.w);
      tt[4] = (short)f2bf(v1.x); tt[5] = (short)f2bf(v1.y);
      tt[6] = (short)f2bf(v1.z); tt[7] = (short)f2bf(v1.w);
      a[ks] = tt;
    }

    f32x4 z = {0.f, 0.f, 0.f, 0.f};
    f32x4 acc[4] = {z, z, z, z};
#pragma unroll
    for (int ct = 0; ct < 4; ++ct)
#pragma unroll
      for (int ks = 0; ks < 4; ++ks)
        acc[ct] = __builtin_amdgcn_mfma_f32_16x16x32_bf16(a[ks], b[ct * 4 + ks],
                                                          acc[ct], 0, 0, 0);
#pragma unroll
    for (int ct = 0; ct < 4; ++ct)
#pragma unroll
      for (int r = 0; r < 4; ++r) {
        int row = row0 + q * 4 + r;                 // D: col=lane&15, row=q*4+reg
        xw[(size_t)row * F_HID + ct * 16 + m] = f2bf(acc[ct][r]);
      }
  } else {
    for (int r = 0; r < 16 && row0 + r < N; ++r) { // tail: col = lane
      const float* xr = x + (size_t)(row0 + r) * F_IN;
      float s = 0.f;
      for (int k = 0; k < F_IN; ++k) s = fmaf(xr[k], W1[k * F_HID + lane], s);
      xw[(size_t)(row0 + r) * F_HID + lane] = f2bf(s);
    }
  }
}

// ---------------------------------------------------------------------------
// Single-block exclusive scan of counts[0..M-1] (+ sentinel). Replaces the
// old scanA+scanC pair (one launch instead of two).
// ---------------------------------------------------------------------------
__global__ __launch_bounds__(1024) void scan1_k(int* __restrict__ a, int M, int E) {
  __shared__ int sm[1024];
  int t = threadIdx.x;
  int per = (M + 1023) >> 10;
  int s0 = t * per;
  int s1 = min(s0 + per, M);
  int s = 0;
  for (int i = s0; i < s1; ++i) s += a[i];
  sm[t] = s;
  __syncthreads();
  for (int off = 1; off < 1024; off <<= 1) {
    int add = (t >= off) ? sm[t - off] : 0;
    __syncthreads();
    sm[t] += add;
    __syncthreads();
  }
  int run = (t > 0) ? sm[t - 1] : 0;    // exclusive prefix of this chunk
  for (int i = s0; i < s1; ++i) {
    int v = a[i];
    a[i] = run;
    run += v;
  }
  if (t == 0) a[M] = E;                 // sentinel
}

// ---------------------------------------------------------------------------
// Multisplit P2: stable partition into bucket-major ebuf.
// ebuf entries are packed u32: (dst & 511) << 17 | src  (src < 131072).
// ---------------------------------------------------------------------------
__global__ __launch_bounds__(256) void partition_k(const int* __restrict__ bases,
                                                   const int* __restrict__ ei,
                                                   unsigned* __restrict__ ebuf,
                                                   int E, int NBLK, int NBUCK) {
  __shared__ uint2 slots[CHUNK];          // 32 KB
  __shared__ int scn[NBMAX], lcur[NBMAX], gadj[NBMAX];
  int t = threadIdx.x, blk = blockIdx.x;
  int e0 = blk * CHUNK;
  int n = min(CHUNK, E - e0);

  int i0 = t * NBLK + blk;
  int cnt = 0, base0 = 0;
  if (t < NBUCK) {
    base0 = bases[i0];
    cnt = bases[i0 + 1] - base0;
  }
  scn[t] = cnt;
  __syncthreads();
  for (int off = 1; off < 256; off <<= 1) {
    int add = (t >= off) ? scn[t - off] : 0;
    __syncthreads();
    scn[t] += add;
    __syncthreads();
  }
  int excl = scn[t] - cnt;
  if (t < NBUCK) { lcur[t] = excl; gadj[t] = base0 - excl; }
  __syncthreads();

  for (int i = t; i < n; i += 256) {
    int s = ei[e0 + i], d = ei[E + e0 + i];
    int pos = atomicAdd(&lcur[((unsigned)d) >> BSH], 1);
    slots[pos] = make_uint2((unsigned)s, (unsigned)d);
  }
  __syncthreads();
  for (int i = t; i < n; i += 256) {
    uint2 sd = slots[i];
    unsigned pk = ((sd.y & 511u) << 17) | sd.x;
    ebuf[gadj[sd.y >> BSH] + i] = pk;
  }
}

// ---------------------------------------------------------------------------
// Bucket-local CSR build. csr entries keep the low-5 dst bits for the
// edge-parallel aggregators: entry = (dst & 31) << 17 | src.
// ---------------------------------------------------------------------------
__global__ __launch_bounds__(BLD_T) void build_k(const unsigned* __restrict__ ebuf,
                                                 const int* __restrict__ bases,
                                                 int* __restrict__ row_ptr,
                                                 int* __restrict__ csr,
                                                 int N, int E, int NBLK) {
  __shared__ int hist[512];
  __shared__ int psc[256];
  __shared__ unsigned stg[BLD_CAP];       // 40 KB
  int t = threadIdx.x, b = blockIdx.x;
  int nodeBase = b << BSH;
  int S = bases[b * NBLK];
  int T = bases[(b + 1) * NBLK];
  int n = T - S;
  bool useLds = (n <= BLD_CAP);

  if (t < 512) hist[t] = 0;
  __syncthreads();
  for (int i = t; i < n; i += BLD_T) {
    unsigned v = ebuf[S + i];
    if (useLds) stg[i] = v;
    atomicAdd(&hist[v >> 17], 1);
  }
  __syncthreads();

  int v0 = 0, v1 = 0, pair = 0;
  if (t < 256) {
    v0 = hist[2 * t]; v1 = hist[2 * t + 1];
    pair = v0 + v1;
    psc[t] = pair;
  }
  __syncthreads();
  for (int off = 1; off < 256; off <<= 1) {
    int add = (t >= off && t < 256) ? psc[t - off] : 0;
    __syncthreads();
    if (t < 256) psc[t] += add;
    __syncthreads();
  }
  if (t < 256) {
    int ep = psc[t] - pair;
    int e0 = ep, e1 = ep + v0;
    int node0 = nodeBase + 2 * t;
    if (node0 < N) row_ptr[node0] = S + e0;
    if (node0 + 1 < N) row_ptr[node0 + 1] = S + e1;
    hist[2 * t] = e0; hist[2 * t + 1] = e1;   // reuse as cursors
  }
  if (b == 0 && t == 0) row_ptr[N] = E;
  __syncthreads();
  for (int i = t; i < n; i += BLD_T) {
    unsigned v = useLds ? stg[i] : ebuf[S + i];
    int pos = atomicAdd(&hist[v >> 17], 1);
    csr[S + pos] = (int)(v & 0x3FFFFFu);   // keep dst&31 in bits 17..21
  }
}

// ---------------------------------------------------------------------------
// FUSED aggregation-1 + bias1 + ReLU + GEMM2 — EDGE-PARALLEL.
// Block owns 32 rows = one contiguous csr range. Threads: slot=t>>3 (32
// parallel edges), part=t&7 (8 cols x 16 B). Accumulate into LDS f32
// acc[32][65] via ds atomics (65-pad: bank=(dl+8p+k)&31, uniform spread).
// Perfect edge balance (no max-of-8-degrees divergence). Then bias+relu ->
// XOR-swizzled hsm -> waves 0/1 run the 64x40 MFMA GEMM -> hw[N][64] bf16
// (cols 0..39).
// ---------------------------------------------------------------------------
__global__ __launch_bounds__(256) void agg1g2_k(const unsigned short* __restrict__ xw,
                                                const int* __restrict__ row_ptr,
                                                const int* __restrict__ csr,
                                                const float* __restrict__ b1,
                                                const unsigned short* __restrict__ w2s,
                                                const float* __restrict__ W2,
                                                unsigned short* __restrict__ hw, int N) {
  __shared__ float acc[32][65];           // 8.3 KB
  __shared__ uint4 hsm[32][8];            // 4 KB, XOR-swizzled on part
  int t = threadIdx.x;
  int wave = t >> 6, lane = t & 63;
  int blockRow0 = blockIdx.x * 32;
  int nrows = min(32, N - blockRow0);
  if (nrows <= 0) return;
  int S = row_ptr[blockRow0];
  int T = row_ptr[blockRow0 + nrows];

  for (int i = t; i < 32 * 65; i += 256) ((float*)acc)[i] = 0.f;
  __syncthreads();

  int g = t >> 3, p = t & 7;
  int e = S + g;
  for (; e + 32 < T; e += 64) {           // 2-wide unroll for MLP
    unsigned v0 = (unsigned)csr[e];
    unsigned v1 = (unsigned)csr[e + 32];
    int src0 = v0 & 0x1FFFF, dl0 = (v0 >> 17) & 31;
    int src1 = v1 & 0x1FFFF, dl1 = (v1 >> 17) & 31;
    uint4 w0 = *(const uint4*)(xw + ((size_t)src0 << 6) + (p << 3));
    uint4 w1 = *(const uint4*)(xw + ((size_t)src1 << 6) + (p << 3));
    float* a0 = &acc[dl0][p << 3];
    atomicAdd(a0 + 0, bflo(w0.x)); atomicAdd(a0 + 1, bfhi(w0.x));
    atomicAdd(a0 + 2, bflo(w0.y)); atomicAdd(a0 + 3, bfhi(w0.y));
    atomicAdd(a0 + 4, bflo(w0.z)); atomicAdd(a0 + 5, bfhi(w0.z));
    atomicAdd(a0 + 6, bflo(w0.w)); atomicAdd(a0 + 7, bfhi(w0.w));
    float* a1 = &acc[dl1][p << 3];
    atomicAdd(a1 + 0, bflo(w1.x)); atomicAdd(a1 + 1, bfhi(w1.x));
    atomicAdd(a1 + 2, bflo(w1.y)); atomicAdd(a1 + 3, bfhi(w1.y));
    atomicAdd(a1 + 4, bflo(w1.z)); atomicAdd(a1 + 5, bfhi(w1.z));
    atomicAdd(a1 + 6, bflo(w1.w)); atomicAdd(a1 + 7, bfhi(w1.w));
  }
  if (e < T) {
    unsigned v = (unsigned)csr[e];
    int src = v & 0x1FFFF, dl = (v >> 17) & 31;
    uint4 w = *(const uint4*)(xw + ((size_t)src << 6) + (p << 3));
    float* a0 = &acc[dl][p << 3];
    atomicAdd(a0 + 0, bflo(w.x)); atomicAdd(a0 + 1, bfhi(w.x));
    atomicAdd(a0 + 2, bflo(w.y)); atomicAdd(a0 + 3, bfhi(w.y));
    atomicAdd(a0 + 4, bflo(w.z)); atomicAdd(a0 + 5, bfhi(w.z));
    atomicAdd(a0 + 6, bflo(w.w)); atomicAdd(a0 + 7, bfhi(w.w));
  }
  __syncthreads();

  // ---- bias + relu + pack into swizzled hsm ----
  {
    int lr = t >> 3;
    int row = blockRow0 + lr;
    if (row < N) {
      int c0 = p << 3;
      float4 bA = *(const float4*)(b1 + c0);
      float4 bB = *(const float4*)(b1 + c0 + 4);
      float r0 = fmaxf(acc[lr][c0 + 0] + bA.x, 0.f);
      float r1 = fmaxf(acc[lr][c0 + 1] + bA.y, 0.f);
      float r2 = fmaxf(acc[lr][c0 + 2] + bA.z, 0.f);
      float r3 = fmaxf(acc[lr][c0 + 3] + bA.w, 0.f);
      float r4 = fmaxf(acc[lr][c0 + 4] + bB.x, 0.f);
      float r5 = fmaxf(acc[lr][c0 + 5] + bB.y, 0.f);
      float r6 = fmaxf(acc[lr][c0 + 6] + bB.z, 0.f);
      float r7 = fmaxf(acc[lr][c0 + 7] + bB.w, 0.f);
      uint4 o = make_uint4(packbf(r0, r1), packbf(r2, r3),
                           packbf(r4, r5), packbf(r6, r7));
      hsm[lr][p ^ (lr & 7)] = o;
    }
  }
  __syncthreads();

  // ---- GEMM2: h[32][64] @ W2[64][40] -> hw (stride 64, cols 0..39) ----
  if (wave < 2) {
    int frow0 = blockRow0 + wave * 16;
    if (frow0 >= N) return;
    int m = lane & 15, q = lane >> 4;
    if (frow0 + 16 <= N) {
      short8 b[6];
#pragma unroll
      for (int f = 0; f < 6; ++f)
        b[f] = *(const short8*)(w2s + f * 512 + lane * 8);
      short8 a[2];
#pragma unroll
      for (int ks = 0; ks < 2; ++ks) {
        int lr = wave * 16 + m;
        int pp = ks * 4 + q;
        a[ks] = *(const short8*)&hsm[lr][pp ^ (lr & 7)];
      }
      f32x4 z = {0.f, 0.f, 0.f, 0.f};
      f32x4 acc2[3] = {z, z, z};
#pragma unroll
      for (int ct = 0; ct < 3; ++ct)
#pragma unroll
        for (int ks = 0; ks < 2; ++ks)
          acc2[ct] = __builtin_amdgcn_mfma_f32_16x16x32_bf16(
              a[ks], b[ct * 2 + ks], acc2[ct], 0, 0, 0);
#pragma unroll
      for (int ct = 0; ct < 3; ++ct)
#pragma unroll
        for (int r = 0; r < 4; ++r) {
          int row2 = frow0 + q * 4 + r;
          int c = ct * 16 + m;
          if (c < F_OUT) hw[(size_t)row2 * F_HID + c] = f2bf(acc2[ct][r]);
        }
    } else {
      for (int r = 0; r < 16; ++r) {            // tail rows (N%16 != 0)
        int row2 = frow0 + r;
        if (row2 >= N) break;
        if (lane < F_OUT) {
          int lr = wave * 16 + r;
          float s = 0.f;
          for (int k = 0; k < F_HID; ++k) {
            const unsigned short* hp =
                (const unsigned short*)&hsm[lr][(k >> 3) ^ (lr & 7)];
            s = fmaf(bf2f(hp[k & 7]), W2[k * F_OUT + lane], s);
          }
          hw[(size_t)row2 * F_HID + lane] = f2bf(s);
        }
      }
    }
  }
}

// ---------------------------------------------------------------------------
// Aggregation layer 2 + bias2 + log_softmax — EDGE-PARALLEL.
// Block owns 32 rows. Gather mapping: slot=t/5 (51 edges in flight),
// part=t%5 (5 x 16 B = 80 B live row) — zero idle lanes during gather.
// Accumulate into LDS f32 acc[32][65] via ds atomics. Then softmax with the
// old (t>>3, t&7) mapping reading LDS.
// ---------------------------------------------------------------------------
__global__ __launch_bounds__(256) void agg2_ls_k(const unsigned short* __restrict__ hw,
                                                 const int* __restrict__ row_ptr,
                                                 const int* __restrict__ csr,
                                                 const float* __restrict__ b2,
                                                 float* __restrict__ out, int N) {
  __shared__ float acc[32][65];           // 8.3 KB (cols 0..39 used)
  int t = threadIdx.x;
  int blockRow0 = blockIdx.x * 32;
  int nrows = min(32, N - blockRow0);
  if (nrows <= 0) return;
  int S = row_ptr[blockRow0];
  int T = row_ptr[blockRow0 + nrows];

  for (int i = t; i < 32 * 65; i += 256) ((float*)acc)[i] = 0.f;
  __syncthreads();

  if (t < 255) {
    int g = t / 5, p = t - g * 5;         // 51 slots x 5 parts
    int e = S + g;
    for (; e + 51 < T; e += 102) {        // 2-wide unroll
      unsigned v0 = (unsigned)csr[e];
      unsigned v1 = (unsigned)csr[e + 51];
      int src0 = v0 & 0x1FFFF, dl0 = (v0 >> 17) & 31;
      int src1 = v1 & 0x1FFFF, dl1 = (v1 >> 17) & 31;
      uint4 w0 = *(const uint4*)(hw + ((size_t)src0 << 6) + (p << 3));
      uint4 w1 = *(const uint4*)(hw + ((size_t)src1 << 6) + (p << 3));
      float* a0 = &acc[dl0][p << 3];
      atomicAdd(a0 + 0, bflo(w0.x)); atomicAdd(a0 + 1, bfhi(w0.x));
      atomicAdd(a0 + 2, bflo(w0.y)); atomicAdd(a0 + 3, bfhi(w0.y));
      atomicAdd(a0 + 4, bflo(w0.z)); atomicAdd(a0 + 5, bfhi(w0.z));
      atomicAdd(a0 + 6, bflo(w0.w)); atomicAdd(a0 + 7, bfhi(w0.w));
      float* a1 = &acc[dl1][p << 3];
      atomicAdd(a1 + 0, bflo(w1.x)); atomicAdd(a1 + 1, bfhi(w1.x));
      atomicAdd(a1 + 2, bflo(w1.y)); atomicAdd(a1 + 3, bfhi(w1.y));
      atomicAdd(a1 + 4, bflo(w1.z)); atomicAdd(a1 + 5, bfhi(w1.z));
      atomicAdd(a1 + 6, bflo(w1.w)); atomicAdd(a1 + 7, bfhi(w1.w));
    }
    if (e < T) {
      unsigned v = (unsigned)csr[e];
      int src = v & 0x1FFFF, dl = (v >> 17) & 31;
      uint4 w = *(const uint4*)(hw + ((size_t)src << 6) + (p << 3));
      float* a0 = &acc[dl][p << 3];
      atomicAdd(a0 + 0, bflo(w.x)); atomicAdd(a0 + 1, bfhi(w.x));
      atomicAdd(a0 + 2, bflo(w.y)); atomicAdd(a0 + 3, bfhi(w.y));
      atomicAdd(a0 + 4, bflo(w.z)); atomicAdd(a0 + 5, bfhi(w.z));
      atomicAdd(a0 + 6, bflo(w.w)); atomicAdd(a0 + 7, bfhi(w.w));
    }
  }
  __syncthreads();

  // ---- bias + log_softmax (old mapping: row=t>>3, part=t&7, parts 0..4) ----
  int lane = t & 63;
  int lr = t >> 3;
  int part = lane & 7;
  int row = blockRow0 + ((t >> 3) & 31);
  bool live = row < N && lr < 32;
  bool valid = live && (part < 5);

  float vj[8];
  float mx = -3.4e38f;
  if (valid) {
    int c0 = part << 3;
    float4 bA = *(const float4*)(b2 + c0);
    float4 bB = *(const float4*)(b2 + c0 + 4);
    vj[0] = acc[lr][c0 + 0] + bA.x; vj[1] = acc[lr][c0 + 1] + bA.y;
    vj[2] = acc[lr][c0 + 2] + bA.z; vj[3] = acc[lr][c0 + 3] + bA.w;
    vj[4] = acc[lr][c0 + 4] + bB.x; vj[5] = acc[lr][c0 + 5] + bB.y;
    vj[6] = acc[lr][c0 + 6] + bB.z; vj[7] = acc[lr][c0 + 7] + bB.w;
#pragma unroll
    for (int q = 0; q < 8; ++q) mx = fmaxf(mx, vj[q]);
  }
#pragma unroll
  for (int off = 1; off < 8; off <<= 1) mx = fmaxf(mx, __shfl_xor(mx, off, 64));
  float ex = 0.f;
  if (valid) {
#pragma unroll
    for (int q = 0; q < 8; ++q) ex += __expf(vj[q] - mx);
  }
#pragma unroll
  for (int off = 1; off < 8; off <<= 1) ex += __shfl_xor(ex, off, 64);
  float lse = __logf(ex) + mx;

  if (valid) {
    int c0 = part << 3;
    float* op = out + (size_t)row * F_OUT + c0;
    *(float4*)op = make_float4(vj[0] - lse, vj[1] - lse, vj[2] - lse, vj[3] - lse);
    *(float4*)(op + 4) = make_float4(vj[4] - lse, vj[5] - lse, vj[6] - lse, vj[7] - lse);
  }
}

// ---------------------------------------------------------------------------
// ws layout (≈33 MB):
//   regA : xw[N,64] bf16
//   regB : ebuf[E] u32 — reused as hw[N,64] bf16 (ebuf dead after build)
//   row_ptr : N+1 | csr : E | counts : M+1 | w2s : 3072
// ---------------------------------------------------------------------------
extern "C" void kernel_launch(void* const* d_in, const int* in_sizes, int n_in,
                              void* d_out, int out_size, void* d_ws, size_t ws_size,
                              hipStream_t stream) {
  const float* x  = (const float*)d_in[0];
  const int*   ei = (const int*)d_in[1];
  const float* W1 = (const float*)d_in[2];
  const float* b1 = (const float*)d_in[3];
  const float* W2 = (const float*)d_in[4];
  const float* b2 = (const float*)d_in[5];

  int N = in_sizes[0] / F_IN;
  int E = in_sizes[1] / 2;

  char* base = (char*)d_ws;
  size_t szA = (size_t)N * F_HID * sizeof(unsigned short);
  size_t szEb = (size_t)E * sizeof(unsigned);
  size_t szHw = (size_t)N * F_HID * sizeof(unsigned short);
  size_t szB = (szEb > szHw) ? szEb : szHw;
  unsigned short* xw = (unsigned short*)base;
  char* regB = base + ((szA + 255) & ~(size_t)255);
  unsigned* ebuf       = (unsigned*)regB;
  unsigned short* hw   = (unsigned short*)regB;
  int* row_ptr = (int*)(regB + ((szB + 255) & ~(size_t)255));
  int* csr     = row_ptr + N + 1;
  int* counts  = csr + E;
  float* out = (float*)d_out;

  int NBLK  = (E + CHUNK - 1) / CHUNK;
  int NBUCK = (N + 511) >> BSH;
  int M = NBUCK * NBLK;
  unsigned short* w2s =
      (unsigned short*)(((uintptr_t)(counts + M + 1) + 63) & ~(uintptr_t)63);
  int gemmGrid = (N + 63) / 64;
  int aggGrid  = (N + 31) / 32;

  // fused: pcount + w2s (blocks 0..NBLK-1) + gemm1 (remaining blocks)
  front_k<<<NBLK + gemmGrid, 256, 0, stream>>>(x, W1, W2, w2s, xw, N,
                                               ei, counts, E, NBLK, NBUCK);

  scan1_k<<<1, 1024, 0, stream>>>(counts, M, E);
  partition_k<<<NBLK, 256, 0, stream>>>(counts, ei, ebuf, E, NBLK, NBUCK);
  build_k<<<NBUCK, BLD_T, 0, stream>>>(ebuf, counts, row_ptr, csr, N, E, NBLK);

  agg1g2_k<<<aggGrid, 256, 0, stream>>>(xw, row_ptr, csr, b1, w2s, W2, hw, N);
  agg2_ls_k<<<aggGrid, 256, 0, stream>>>(hw, row_ptr, csr, b2, out, N);
}

// Round 5
// 331.822 us; speedup vs baseline: 3.4783x; 3.4783x over previous
//
#include <hip/hip_runtime.h>
#include <cstdint>
#include <cstddef>

#define F_IN  128
#define F_HID 64
#define F_OUT 40

#define BSH   9     // bucket = dst >> 9 (512 nodes/bucket)
#define NBMAX 256   // supports N <= 131072
#define CHUNK 4096  // edges per partition block

#define BLD_T   512   // build_k threads
#define BLD_CAP 10240 // LDS-staged edges per bucket (40 KB)

typedef __attribute__((ext_vector_type(8))) short short8;   // 8 bf16 = 4 VGPR
typedef __attribute__((ext_vector_type(4))) float f32x4;    // MFMA C/D

// bf16 <-> f32 helpers (RNE on pack; values are finite)
__device__ __forceinline__ unsigned short f2bf(float f) {
  unsigned u = __float_as_uint(f);
  u += 0x7fffu + ((u >> 16) & 1u);
  return (unsigned short)(u >> 16);
}
__device__ __forceinline__ float bf2f(unsigned short b) {
  return __uint_as_float((unsigned)b << 16);
}
__device__ __forceinline__ float bflo(unsigned u) { return __uint_as_float(u << 16); }
__device__ __forceinline__ float bfhi(unsigned u) { return __uint_as_float(u & 0xffff0000u); }
__device__ __forceinline__ unsigned packbf(float lo, float hi) {
  return (unsigned)f2bf(lo) | ((unsigned)f2bf(hi) << 16);
}

// ---------------------------------------------------------------------------
// FRONT (fused): blocks [0,NBLK) run pcount (block 0 additionally emits the
// w2s MFMA-swizzled copy of W2); blocks [NBLK,+gemmBlks) run MFMA GEMM1,
// each converting W1 into a 16 KB LDS B-fragment copy first.
// B-frag (16x16x32): lane holds B^T[n=lane&15][k=(lane>>4)*8+j], j=0..7.
// ---------------------------------------------------------------------------
__global__ __launch_bounds__(256) void front_k(const float* __restrict__ x,
                                               const float* __restrict__ W1,
                                               const float* __restrict__ W2,
                                               unsigned short* __restrict__ w2s,
                                               unsigned short* __restrict__ xw, int N,
                                               const int* __restrict__ ei,
                                               int* __restrict__ counts,
                                               int E, int NBLK, int NBUCK) {
  __shared__ int lh[NBMAX];
  __shared__ unsigned short w1l[8192];    // 16 KB swizzled W1 (gemm1 branch)
  int t = threadIdx.x;

  if ((int)blockIdx.x < NBLK) {
    // ---- pcount ----
    int blk = blockIdx.x;
    lh[t] = 0;
    __syncthreads();
    int e0 = blk * CHUNK;
    int n = min(CHUNK, E - e0);
    for (int i = t; i < n; i += 256)
      atomicAdd(&lh[((unsigned)ei[E + e0 + i]) >> BSH], 1);
    __syncthreads();
    if (t < NBUCK) counts[t * NBLK + blk] = lh[t];
    if (blk == 0) {
      // emit swizzled W2 (cols >= 40 zero) for GEMM2
      for (int i = t; i < 3072; i += 256) {
        int f = i >> 9, r = i & 511;
        int lane = r >> 3, jj = r & 7;
        int ct = f >> 1, ks = f & 1;
        int n2 = ct * 16 + (lane & 15);
        int k = ks * 32 + (lane >> 4) * 8 + jj;
        w2s[i] = (n2 < F_OUT) ? f2bf(W2[k * F_OUT + n2]) : (unsigned short)0;
      }
    }
    return;
  }

  // ---- gemm1: convert W1 -> LDS (all threads, coalesced global reads) ----
  {
    int k = t >> 1, n0 = (t & 1) * 32;       // thread owns W1[k][n0..n0+32)
    const float4* wp = (const float4*)(W1 + k * F_HID + n0);
    float4 v[8];
#pragma unroll
    for (int u = 0; u < 8; ++u) v[u] = wp[u];
#pragma unroll
    for (int u = 0; u < 32; ++u) {
      int n = n0 + u;
      float f = ((const float*)v)[u];
      int idx = ((n >> 4) * 4 + (k >> 5)) * 512 +
                (((k >> 3) & 3) * 16 + (n & 15)) * 8 + (k & 7);
      w1l[idx] = f2bf(f);
    }
  }
  __syncthreads();

  int gblk = blockIdx.x - NBLK;
  int lane = t & 63;
  int wid  = gblk * 4 + (t >> 6);
  int row0 = wid * 16;
  if (row0 >= N) return;
  int m = lane & 15, q = lane >> 4;

  if (row0 + 16 <= N) {
    short8 b[16];
#pragma unroll
    for (int f = 0; f < 16; ++f)
      b[f] = *(const short8*)(w1l + f * 512 + lane * 8);

    short8 a[4];
#pragma unroll
    for (int ks = 0; ks < 4; ++ks) {
      const float* xp = x + (size_t)(row0 + m) * F_IN + ks * 32 + q * 8;
      float4 v0 = *(const float4*)xp;
      float4 v1 = *(const float4*)(xp + 4);
      short8 tt;
      tt[0] = (short)f2bf(v0.x); tt[1] = (short)f2bf(v0.y);
      tt[2] = (short)f2bf(v0.z); tt[3] = (short)f2bf(v0.w);
      tt[4] = (short)f2bf(v1.x); tt[5] = (short)f2bf(v1.y);
      tt[6] = (short)f2bf(v1.z); tt[7] = (short)f2bf(v1.w);
      a[ks] = tt;
    }

    f32x4 z = {0.f, 0.f, 0.f, 0.f};
    f32x4 acc[4] = {z, z, z, z};
#pragma unroll
    for (int ct = 0; ct < 4; ++ct)
#pragma unroll
      for (int ks = 0; ks < 4; ++ks)
        acc[ct] = __builtin_amdgcn_mfma_f32_16x16x32_bf16(a[ks], b[ct * 4 + ks],
                                                          acc[ct], 0, 0, 0);
#pragma unroll
    for (int ct = 0; ct < 4; ++ct)
#pragma unroll
      for (int r = 0; r < 4; ++r) {
        int row = row0 + q * 4 + r;                 // D: col=lane&15, row=q*4+reg
        xw[(size_t)row * F_HID + ct * 16 + m] = f2bf(acc[ct][r]);
      }
  } else {
    for (int r = 0; r < 16 && row0 + r < N; ++r) { // tail: col = lane
      const float* xr = x + (size_t)(row0 + r) * F_IN;
      float s = 0.f;
      for (int k = 0; k < F_IN; ++k) s = fmaf(xr[k], W1[k * F_HID + lane], s);
      xw[(size_t)(row0 + r) * F_HID + lane] = f2bf(s);
    }
  }
}

// ---------------------------------------------------------------------------
// Single-block exclusive scan of counts[0..M-1] (+ sentinel). Replaces the
// old scanA+scanC pair (one launch instead of two). Verified correct in R3.
// ---------------------------------------------------------------------------
__global__ __launch_bounds__(1024) void scan1_k(int* __restrict__ a, int M, int E) {
  __shared__ int sm[1024];
  int t = threadIdx.x;
  int per = (M + 1023) >> 10;
  int s0 = t * per;
  int s1 = min(s0 + per, M);
  int s = 0;
  for (int i = s0; i < s1; ++i) s += a[i];
  sm[t] = s;
  __syncthreads();
  for (int off = 1; off < 1024; off <<= 1) {
    int add = (t >= off) ? sm[t - off] : 0;
    __syncthreads();
    sm[t] += add;
    __syncthreads();
  }
  int run = (t > 0) ? sm[t - 1] : 0;    // exclusive prefix of this chunk
  for (int i = s0; i < s1; ++i) {
    int v = a[i];
    a[i] = run;
    run += v;
  }
  if (t == 0) a[M] = E;                 // sentinel
}

// ---------------------------------------------------------------------------
// Multisplit P2: stable partition into bucket-major ebuf.
// ebuf entries are packed u32: (dst & 511) << 17 | src  (src < 131072).
// ---------------------------------------------------------------------------
__global__ __launch_bounds__(256) void partition_k(const int* __restrict__ bases,
                                                   const int* __restrict__ ei,
                                                   unsigned* __restrict__ ebuf,
                                                   int E, int NBLK, int NBUCK) {
  __shared__ uint2 slots[CHUNK];          // 32 KB
  __shared__ int scn[NBMAX], lcur[NBMAX], gadj[NBMAX];
  int t = threadIdx.x, blk = blockIdx.x;
  int e0 = blk * CHUNK;
  int n = min(CHUNK, E - e0);

  int i0 = t * NBLK + blk;
  int cnt = 0, base0 = 0;
  if (t < NBUCK) {
    base0 = bases[i0];
    cnt = bases[i0 + 1] - base0;
  }
  scn[t] = cnt;
  __syncthreads();
  for (int off = 1; off < 256; off <<= 1) {
    int add = (t >= off) ? scn[t - off] : 0;
    __syncthreads();
    scn[t] += add;
    __syncthreads();
  }
  int excl = scn[t] - cnt;
  if (t < NBUCK) { lcur[t] = excl; gadj[t] = base0 - excl; }
  __syncthreads();

  for (int i = t; i < n; i += 256) {
    int s = ei[e0 + i], d = ei[E + e0 + i];
    int pos = atomicAdd(&lcur[((unsigned)d) >> BSH], 1);
    slots[pos] = make_uint2((unsigned)s, (unsigned)d);
  }
  __syncthreads();
  for (int i = t; i < n; i += 256) {
    uint2 sd = slots[i];
    unsigned pk = ((sd.y & 511u) << 17) | sd.x;
    ebuf[gadj[sd.y >> BSH] + i] = pk;
  }
}

// ---------------------------------------------------------------------------
// Bucket-local CSR build: LDS-stage the bucket's packed edges (read once),
// LDS histogram + scan -> row_ptr; LDS cursor fill. csr = plain src.
// ---------------------------------------------------------------------------
__global__ __launch_bounds__(BLD_T) void build_k(const unsigned* __restrict__ ebuf,
                                                 const int* __restrict__ bases,
                                                 int* __restrict__ row_ptr,
                                                 int* __restrict__ csr,
                                                 int N, int E, int NBLK) {
  __shared__ int hist[512];
  __shared__ int psc[256];
  __shared__ unsigned stg[BLD_CAP];       // 40 KB
  int t = threadIdx.x, b = blockIdx.x;
  int nodeBase = b << BSH;
  int S = bases[b * NBLK];
  int T = bases[(b + 1) * NBLK];
  int n = T - S;
  bool useLds = (n <= BLD_CAP);

  if (t < 512) hist[t] = 0;
  __syncthreads();
  for (int i = t; i < n; i += BLD_T) {
    unsigned v = ebuf[S + i];
    if (useLds) stg[i] = v;
    atomicAdd(&hist[v >> 17], 1);
  }
  __syncthreads();

  int v0 = 0, v1 = 0, pair = 0;
  if (t < 256) {
    v0 = hist[2 * t]; v1 = hist[2 * t + 1];
    pair = v0 + v1;
    psc[t] = pair;
  }
  __syncthreads();
  for (int off = 1; off < 256; off <<= 1) {
    int add = (t >= off && t < 256) ? psc[t - off] : 0;
    __syncthreads();
    if (t < 256) psc[t] += add;
    __syncthreads();
  }
  if (t < 256) {
    int ep = psc[t] - pair;
    int e0 = ep, e1 = ep + v0;
    int node0 = nodeBase + 2 * t;
    if (node0 < N) row_ptr[node0] = S + e0;
    if (node0 + 1 < N) row_ptr[node0 + 1] = S + e1;
    hist[2 * t] = e0; hist[2 * t + 1] = e1;   // reuse as cursors
  }
  if (b == 0 && t == 0) row_ptr[N] = E;
  __syncthreads();
  for (int i = t; i < n; i += BLD_T) {
    unsigned v = useLds ? stg[i] : ebuf[S + i];
    int pos = atomicAdd(&hist[v >> 17], 1);
    csr[S + pos] = (int)(v & 0x1FFFFu);
  }
}

// ---------------------------------------------------------------------------
// FUSED aggregation-1 + bias1 + ReLU + GEMM2 (row-parallel, lane-private).
// Wave = 8 rows (lane: row=lane>>3, part=lane&7 owning 8 cols = 16 B).
// Gather loop 4-wide unrolled. After aggregation, h[32][64] staged in
// XOR-swizzled LDS; waves 0/1 run the 64x40 MFMA GEMM -> hw[N][64] bf16
// (cols 0..39 valid, stride 64 for 128-B line alignment).
// ---------------------------------------------------------------------------
__global__ __launch_bounds__(256) void agg1g2_k(const unsigned short* __restrict__ xw,
                                                const int* __restrict__ row_ptr,
                                                const int* __restrict__ csr,
                                                const float* __restrict__ b1,
                                                const unsigned short* __restrict__ w2s,
                                                const float* __restrict__ W2,
                                                unsigned short* __restrict__ hw, int N) {
  __shared__ uint4 hsm[32][8];            // 4 KB, XOR-swizzled on part
  int t = threadIdx.x;
  int wave = t >> 6, lane = t & 63;
  int blockRow0 = blockIdx.x * 32;
  int rowBase = blockRow0 + wave * 8;
  int row = rowBase + (lane >> 3);
  int part = lane & 7;
  bool live = row < N;

  int start = live ? row_ptr[row] : 0;
  int end   = live ? row_ptr[row + 1] : 0;

  float acc[8], bcc[8];
#pragma unroll
  for (int j = 0; j < 8; ++j) { acc[j] = 0.f; bcc[j] = 0.f; }

  int i = start;
  for (; i + 3 < end; i += 4) {
    int s0 = csr[i];
    int s1 = csr[i + 1];
    int s2 = csr[i + 2];
    int s3 = csr[i + 3];
    uint4 v0 = *(const uint4*)(xw + ((size_t)s0 << 6) + (part << 3));
    uint4 v1 = *(const uint4*)(xw + ((size_t)s1 << 6) + (part << 3));
    uint4 v2 = *(const uint4*)(xw + ((size_t)s2 << 6) + (part << 3));
    uint4 v3 = *(const uint4*)(xw + ((size_t)s3 << 6) + (part << 3));
    acc[0] += bflo(v0.x); acc[1] += bfhi(v0.x);
    acc[2] += bflo(v0.y); acc[3] += bfhi(v0.y);
    acc[4] += bflo(v0.z); acc[5] += bfhi(v0.z);
    acc[6] += bflo(v0.w); acc[7] += bfhi(v0.w);
    bcc[0] += bflo(v1.x); bcc[1] += bfhi(v1.x);
    bcc[2] += bflo(v1.y); bcc[3] += bfhi(v1.y);
    bcc[4] += bflo(v1.z); bcc[5] += bfhi(v1.z);
    bcc[6] += bflo(v1.w); bcc[7] += bfhi(v1.w);
    acc[0] += bflo(v2.x); acc[1] += bfhi(v2.x);
    acc[2] += bflo(v2.y); acc[3] += bfhi(v2.y);
    acc[4] += bflo(v2.z); acc[5] += bfhi(v2.z);
    acc[6] += bflo(v2.w); acc[7] += bfhi(v2.w);
    bcc[0] += bflo(v3.x); bcc[1] += bfhi(v3.x);
    bcc[2] += bflo(v3.y); bcc[3] += bfhi(v3.y);
    bcc[4] += bflo(v3.z); bcc[5] += bfhi(v3.z);
    bcc[6] += bflo(v3.w); bcc[7] += bfhi(v3.w);
  }
  for (; i < end; ++i) {
    int s = csr[i];
    uint4 v = *(const uint4*)(xw + ((size_t)s << 6) + (part << 3));
    acc[0] += bflo(v.x); acc[1] += bfhi(v.x);
    acc[2] += bflo(v.y); acc[3] += bfhi(v.y);
    acc[4] += bflo(v.z); acc[5] += bfhi(v.z);
    acc[6] += bflo(v.w); acc[7] += bfhi(v.w);
  }

  if (live) {
    int c0 = part << 3;
    float4 bA = *(const float4*)(b1 + c0);
    float4 bB = *(const float4*)(b1 + c0 + 4);
    float r0 = fmaxf(acc[0] + bcc[0] + bA.x, 0.f);
    float r1 = fmaxf(acc[1] + bcc[1] + bA.y, 0.f);
    float r2 = fmaxf(acc[2] + bcc[2] + bA.z, 0.f);
    float r3 = fmaxf(acc[3] + bcc[3] + bA.w, 0.f);
    float r4 = fmaxf(acc[4] + bcc[4] + bB.x, 0.f);
    float r5 = fmaxf(acc[5] + bcc[5] + bB.y, 0.f);
    float r6 = fmaxf(acc[6] + bcc[6] + bB.z, 0.f);
    float r7 = fmaxf(acc[7] + bcc[7] + bB.w, 0.f);
    uint4 o = make_uint4(packbf(r0, r1), packbf(r2, r3),
                         packbf(r4, r5), packbf(r6, r7));
    int lr = row - blockRow0;
    hsm[lr][part ^ (lr & 7)] = o;
  }
  __syncthreads();

  // ---- GEMM2: h[32][64] @ W2[64][40] -> hw (stride 64, cols 0..39) ----
  if (wave < 2) {
    int frow0 = blockRow0 + wave * 16;
    if (frow0 >= N) return;
    int m = lane & 15, q = lane >> 4;
    if (frow0 + 16 <= N) {
      short8 b[6];
#pragma unroll
      for (int f = 0; f < 6; ++f)
        b[f] = *(const short8*)(w2s + f * 512 + lane * 8);
      short8 a[2];
#pragma unroll
      for (int ks = 0; ks < 2; ++ks) {
        int lr = wave * 16 + m;
        int pp = ks * 4 + q;
        a[ks] = *(const short8*)&hsm[lr][pp ^ (lr & 7)];
      }
      f32x4 z = {0.f, 0.f, 0.f, 0.f};
      f32x4 acc2[3] = {z, z, z};
#pragma unroll
      for (int ct = 0; ct < 3; ++ct)
#pragma unroll
        for (int ks = 0; ks < 2; ++ks)
          acc2[ct] = __builtin_amdgcn_mfma_f32_16x16x32_bf16(
              a[ks], b[ct * 2 + ks], acc2[ct], 0, 0, 0);
#pragma unroll
      for (int ct = 0; ct < 3; ++ct)
#pragma unroll
        for (int r = 0; r < 4; ++r) {
          int row2 = frow0 + q * 4 + r;
          int c = ct * 16 + m;
          if (c < F_OUT) hw[(size_t)row2 * F_HID + c] = f2bf(acc2[ct][r]);
        }
    } else {
      for (int r = 0; r < 16; ++r) {            // tail rows (N%16 != 0)
        int row2 = frow0 + r;
        if (row2 >= N) break;
        if (lane < F_OUT) {
          int lr = wave * 16 + r;
          float s = 0.f;
          for (int k = 0; k < F_HID; ++k) {
            const unsigned short* hp =
                (const unsigned short*)&hsm[lr][(k >> 3) ^ (lr & 7)];
            s = fmaf(bf2f(hp[k & 7]), W2[k * F_OUT + lane], s);
          }
          hw[(size_t)row2 * F_HID + lane] = f2bf(s);
        }
      }
    }
  }
}

// ---------------------------------------------------------------------------
// Aggregation layer 2 + bias2 + log_softmax — 12 rows x 5 parts per wave.
// hw rows are 128-B aligned; cols 0..39 live (5 x 16-B parts). Each 5-lane
// group owns one row: 94% lane utilization during the gather (vs 62% with
// the 8-part mapping where parts 5..7 idled). Softmax reduces across the
// 5-lane group via explicit __shfl.
// ---------------------------------------------------------------------------
__global__ __launch_bounds__(256) void agg2_ls_k(const unsigned short* __restrict__ hw,
                                                 const int* __restrict__ row_ptr,
                                                 const int* __restrict__ csr,
                                                 const float* __restrict__ b2,
                                                 float* __restrict__ out, int N) {
  int t = threadIdx.x;
  int wave = t >> 6, lane = t & 63;
  int grp = lane / 5;                      // 12 groups; lanes 60..63 idle
  int part = lane - grp * 5;
  int row = blockIdx.x * 48 + wave * 12 + grp;
  bool live = (grp < 12) && (row < N);

  int start = live ? row_ptr[row] : 0;
  int end   = live ? row_ptr[row + 1] : 0;

  float acc[8], bcc[8];
#pragma unroll
  for (int j = 0; j < 8; ++j) { acc[j] = 0.f; bcc[j] = 0.f; }

  int i = start;
  for (; i + 3 < end; i += 4) {
    int s0 = csr[i];
    int s1 = csr[i + 1];
    int s2 = csr[i + 2];
    int s3 = csr[i + 3];
    uint4 v0 = *(const uint4*)(hw + ((size_t)s0 << 6) + (part << 3));
    uint4 v1 = *(const uint4*)(hw + ((size_t)s1 << 6) + (part << 3));
    uint4 v2 = *(const uint4*)(hw + ((size_t)s2 << 6) + (part << 3));
    uint4 v3 = *(const uint4*)(hw + ((size_t)s3 << 6) + (part << 3));
    acc[0] += bflo(v0.x); acc[1] += bfhi(v0.x);
    acc[2] += bflo(v0.y); acc[3] += bfhi(v0.y);
    acc[4] += bflo(v0.z); acc[5] += bfhi(v0.z);
    acc[6] += bflo(v0.w); acc[7] += bfhi(v0.w);
    bcc[0] += bflo(v1.x); bcc[1] += bfhi(v1.x);
    bcc[2] += bflo(v1.y); bcc[3] += bfhi(v1.y);
    bcc[4] += bflo(v1.z); bcc[5] += bfhi(v1.z);
    bcc[6] += bflo(v1.w); bcc[7] += bfhi(v1.w);
    acc[0] += bflo(v2.x); acc[1] += bfhi(v2.x);
    acc[2] += bflo(v2.y); acc[3] += bfhi(v2.y);
    acc[4] += bflo(v2.z); acc[5] += bfhi(v2.z);
    acc[6] += bflo(v2.w); acc[7] += bfhi(v2.w);
    bcc[0] += bflo(v3.x); bcc[1] += bfhi(v3.x);
    bcc[2] += bflo(v3.y); bcc[3] += bfhi(v3.y);
    bcc[4] += bflo(v3.z); bcc[5] += bfhi(v3.z);
    bcc[6] += bflo(v3.w); bcc[7] += bfhi(v3.w);
  }
  if (i < end) {                     // remainder (0..3 edges)
    for (; i < end; ++i) {
      int s = csr[i];
      uint4 v = *(const uint4*)(hw + ((size_t)s << 6) + (part << 3));
      acc[0] += bflo(v.x); acc[1] += bfhi(v.x);
      acc[2] += bflo(v.y); acc[3] += bfhi(v.y);
      acc[4] += bflo(v.z); acc[5] += bfhi(v.z);
      acc[6] += bflo(v.w); acc[7] += bfhi(v.w);
    }
  }

  float vj[8];
  float mx = -3.4e38f;
  if (live) {
    int c0 = part << 3;
    float4 bA = *(const float4*)(b2 + c0);
    float4 bB = *(const float4*)(b2 + c0 + 4);
    vj[0] = acc[0] + bcc[0] + bA.x; vj[1] = acc[1] + bcc[1] + bA.y;
    vj[2] = acc[2] + bcc[2] + bA.z; vj[3] = acc[3] + bcc[3] + bA.w;
    vj[4] = acc[4] + bcc[4] + bB.x; vj[5] = acc[5] + bcc[5] + bB.y;
    vj[6] = acc[6] + bcc[6] + bB.z; vj[7] = acc[7] + bcc[7] + bB.w;
#pragma unroll
    for (int q = 0; q < 8; ++q) mx = fmaxf(mx, vj[q]);
  }
  // group (5-lane) reductions via explicit shfl; idle lanes carry -inf / 0
  int g0 = (grp < 12 ? grp : 0) * 5;
  float mxAll = mx;
#pragma unroll
  for (int q = 0; q < 5; ++q) mxAll = fmaxf(mxAll, __shfl(mx, g0 + q, 64));
  float ex = 0.f;
  if (live) {
#pragma unroll
    for (int q = 0; q < 8; ++q) ex += __expf(vj[q] - mxAll);
  }
  float exAll = 0.f;
#pragma unroll
  for (int q = 0; q < 5; ++q) exAll += __shfl(ex, g0 + q, 64);
  float lse = __logf(exAll) + mxAll;

  if (live) {
    int c0 = part << 3;
    float* op = out + (size_t)row * F_OUT + c0;
    *(float4*)op = make_float4(vj[0] - lse, vj[1] - lse, vj[2] - lse, vj[3] - lse);
    *(float4*)(op + 4) = make_float4(vj[4] - lse, vj[5] - lse, vj[6] - lse, vj[7] - lse);
  }
}

// ---------------------------------------------------------------------------
// ws layout (≈33 MB):
//   regA : xw[N,64] bf16
//   regB : ebuf[E] u32 — reused as hw[N,64] bf16 (ebuf dead after build)
//   row_ptr : N+1 | csr : E | counts : M+1 | w2s : 3072
// ---------------------------------------------------------------------------
extern "C" void kernel_launch(void* const* d_in, const int* in_sizes, int n_in,
                              void* d_out, int out_size, void* d_ws, size_t ws_size,
                              hipStream_t stream) {
  const float* x  = (const float*)d_in[0];
  const int*   ei = (const int*)d_in[1];
  const float* W1 = (const float*)d_in[2];
  const float* b1 = (const float*)d_in[3];
  const float* W2 = (const float*)d_in[4];
  const float* b2 = (const float*)d_in[5];

  int N = in_sizes[0] / F_IN;
  int E = in_sizes[1] / 2;

  char* base = (char*)d_ws;
  size_t szA = (size_t)N * F_HID * sizeof(unsigned short);
  size_t szEb = (size_t)E * sizeof(unsigned);
  size_t szHw = (size_t)N * F_HID * sizeof(unsigned short);
  size_t szB = (szEb > szHw) ? szEb : szHw;
  unsigned short* xw = (unsigned short*)base;
  char* regB = base + ((szA + 255) & ~(size_t)255);
  unsigned* ebuf       = (unsigned*)regB;
  unsigned short* hw   = (unsigned short*)regB;
  int* row_ptr = (int*)(regB + ((szB + 255) & ~(size_t)255));
  int* csr     = row_ptr + N + 1;
  int* counts  = csr + E;
  float* out = (float*)d_out;

  int NBLK  = (E + CHUNK - 1) / CHUNK;
  int NBUCK = (N + 511) >> BSH;
  int M = NBUCK * NBLK;
  unsigned short* w2s =
      (unsigned short*)(((uintptr_t)(counts + M + 1) + 63) & ~(uintptr_t)63);
  int gemmGrid = (N + 63) / 64;
  int aggGrid1 = (N + 31) / 32;      // agg1g2: 32 rows per block
  int aggGrid2 = (N + 47) / 48;      // agg2: 48 rows per block (12/wave)

  // fused: pcount + w2s (blocks 0..NBLK-1) + gemm1 (remaining blocks)
  front_k<<<NBLK + gemmGrid, 256, 0, stream>>>(x, W1, W2, w2s, xw, N,
                                               ei, counts, E, NBLK, NBUCK);

  scan1_k<<<1, 1024, 0, stream>>>(counts, M, E);
  partition_k<<<NBLK, 256, 0, stream>>>(counts, ei, ebuf, E, NBLK, NBUCK);
  build_k<<<NBUCK, BLD_T, 0, stream>>>(ebuf, counts, row_ptr, csr, N, E, NBLK);

  agg1g2_k<<<aggGrid1, 256, 0, stream>>>(xw, row_ptr, csr, b1, w2s, W2, hw, N);
  agg2_ls_k<<<aggGrid2, 256, 0, stream>>>(hw, row_ptr, csr, b2, out, N);
}

// Round 6
// 326.277 us; speedup vs baseline: 3.5374x; 1.0170x over previous
//
#include <hip/hip_runtime.h>
#include <hip/hip_cooperative_groups.h>
#include <cstdint>
#include <cstddef>

namespace cg = cooperative_groups;

#define F_IN  128
#define F_HID 64
#define F_OUT 40

#define BSH   9     // bucket = dst >> 9 (512 nodes/bucket)
#define NBMAX 256   // supports N <= 131072
#define CHUNK 4096  // edges per partition block

#define BLD_T   512   // build_k threads
#define BLD_CAP 10240 // LDS-staged edges per bucket (40 KB)

typedef __attribute__((ext_vector_type(8))) short short8;   // 8 bf16 = 4 VGPR
typedef __attribute__((ext_vector_type(4))) float f32x4;    // MFMA C/D

// bf16 <-> f32 helpers (RNE on pack; values are finite)
__device__ __forceinline__ unsigned short f2bf(float f) {
  unsigned u = __float_as_uint(f);
  u += 0x7fffu + ((u >> 16) & 1u);
  return (unsigned short)(u >> 16);
}
__device__ __forceinline__ float bf2f(unsigned short b) {
  return __uint_as_float((unsigned)b << 16);
}
__device__ __forceinline__ float bflo(unsigned u) { return __uint_as_float(u << 16); }
__device__ __forceinline__ float bfhi(unsigned u) { return __uint_as_float(u & 0xffff0000u); }
__device__ __forceinline__ unsigned packbf(float lo, float hi) {
  return (unsigned)f2bf(lo) | ((unsigned)f2bf(hi) << 16);
}

// ---------------------------------------------------------------------------
// FRONT (fused): blocks [0,NBLK) run pcount (block 0 additionally emits the
// w2s MFMA-swizzled copy of W2); blocks [NBLK,+gemmBlks) run MFMA GEMM1,
// each converting W1 into a 16 KB LDS B-fragment copy first.
// counts layout: [NBUCK][NB1] with NB1 = NBLK+1 (col NBLK reserved for
// row totals, filled by scanR_k).
// ---------------------------------------------------------------------------
__global__ __launch_bounds__(256) void front_k(const float* __restrict__ x,
                                               const float* __restrict__ W1,
                                               const float* __restrict__ W2,
                                               unsigned short* __restrict__ w2s,
                                               unsigned short* __restrict__ xw, int N,
                                               const int* __restrict__ ei,
                                               int* __restrict__ counts,
                                               int E, int NBLK, int NB1, int NBUCK) {
  __shared__ int lh[NBMAX];
  __shared__ unsigned short w1l[8192];    // 16 KB swizzled W1 (gemm1 branch)
  int t = threadIdx.x;

  if ((int)blockIdx.x < NBLK) {
    // ---- pcount ----
    int blk = blockIdx.x;
    lh[t] = 0;
    __syncthreads();
    int e0 = blk * CHUNK;
    int n = min(CHUNK, E - e0);
    for (int i = t; i < n; i += 256)
      atomicAdd(&lh[((unsigned)ei[E + e0 + i]) >> BSH], 1);
    __syncthreads();
    if (t < NBUCK) counts[t * NB1 + blk] = lh[t];
    if (blk == 0) {
      // emit swizzled W2 (cols >= 40 zero) for GEMM2
      for (int i = t; i < 3072; i += 256) {
        int f = i >> 9, r = i & 511;
        int lane = r >> 3, jj = r & 7;
        int ct = f >> 1, ks = f & 1;
        int n2 = ct * 16 + (lane & 15);
        int k = ks * 32 + (lane >> 4) * 8 + jj;
        w2s[i] = (n2 < F_OUT) ? f2bf(W2[k * F_OUT + n2]) : (unsigned short)0;
      }
    }
    return;
  }

  // ---- gemm1: convert W1 -> LDS (all threads, coalesced global reads) ----
  {
    int k = t >> 1, n0 = (t & 1) * 32;       // thread owns W1[k][n0..n0+32)
    const float4* wp = (const float4*)(W1 + k * F_HID + n0);
    float4 v[8];
#pragma unroll
    for (int u = 0; u < 8; ++u) v[u] = wp[u];
#pragma unroll
    for (int u = 0; u < 32; ++u) {
      int n = n0 + u;
      float f = ((const float*)v)[u];
      int idx = ((n >> 4) * 4 + (k >> 5)) * 512 +
                (((k >> 3) & 3) * 16 + (n & 15)) * 8 + (k & 7);
      w1l[idx] = f2bf(f);
    }
  }
  __syncthreads();

  int gblk = blockIdx.x - NBLK;
  int lane = t & 63;
  int wid  = gblk * 4 + (t >> 6);
  int row0 = wid * 16;
  if (row0 >= N) return;
  int m = lane & 15, q = lane >> 4;

  if (row0 + 16 <= N) {
    short8 b[16];
#pragma unroll
    for (int f = 0; f < 16; ++f)
      b[f] = *(const short8*)(w1l + f * 512 + lane * 8);

    short8 a[4];
#pragma unroll
    for (int ks = 0; ks < 4; ++ks) {
      const float* xp = x + (size_t)(row0 + m) * F_IN + ks * 32 + q * 8;
      float4 v0 = *(const float4*)xp;
      float4 v1 = *(const float4*)(xp + 4);
      short8 tt;
      tt[0] = (short)f2bf(v0.x); tt[1] = (short)f2bf(v0.y);
      tt[2] = (short)f2bf(v0.z); tt[3] = (short)f2bf(v0.w);
      tt[4] = (short)f2bf(v1.x); tt[5] = (short)f2bf(v1.y);
      tt[6] = (short)f2bf(v1.z); tt[7] = (short)f2bf(v1.w);
      a[ks] = tt;
    }

    f32x4 z = {0.f, 0.f, 0.f, 0.f};
    f32x4 acc[4] = {z, z, z, z};
#pragma unroll
    for (int ct = 0; ct < 4; ++ct)
#pragma unroll
      for (int ks = 0; ks < 4; ++ks)
        acc[ct] = __builtin_amdgcn_mfma_f32_16x16x32_bf16(a[ks], b[ct * 4 + ks],
                                                          acc[ct], 0, 0, 0);
#pragma unroll
    for (int ct = 0; ct < 4; ++ct)
#pragma unroll
      for (int r = 0; r < 4; ++r) {
        int row = row0 + q * 4 + r;                 // D: col=lane&15, row=q*4+reg
        xw[(size_t)row * F_HID + ct * 16 + m] = f2bf(acc[ct][r]);
      }
  } else {
    for (int r = 0; r < 16 && row0 + r < N; ++r) { // tail: col = lane
      const float* xr = x + (size_t)(row0 + r) * F_IN;
      float s = 0.f;
      for (int k = 0; k < F_IN; ++k) s = fmaf(xr[k], W1[k * F_HID + lane], s);
      xw[(size_t)(row0 + r) * F_HID + lane] = f2bf(s);
    }
  }
}

// ---------------------------------------------------------------------------
// Row-wise exclusive scan: block b scans counts[b][0..NBLK) in place and
// writes the row total to counts[b][NBLK]. 196 parallel blocks — replaces
// the serial single-block scan (R4's 126 µs lesson).
// ---------------------------------------------------------------------------
__global__ __launch_bounds__(256) void scanR_k(int* __restrict__ counts,
                                               int NBLK, int NB1) {
  __shared__ int sm[512];
  __shared__ int psc[256];
  int t = threadIdx.x;
  int* c = counts + blockIdx.x * NB1;

  sm[t]       = (t < NBLK)       ? c[t]       : 0;
  sm[t + 256] = (t + 256 < NBLK) ? c[t + 256] : 0;
  __syncthreads();

  int v0 = sm[2 * t], v1 = sm[2 * t + 1];
  int pair = v0 + v1;
  psc[t] = pair;
  __syncthreads();
  for (int off = 1; off < 256; off <<= 1) {
    int add = (t >= off) ? psc[t - off] : 0;
    __syncthreads();
    psc[t] += add;
    __syncthreads();
  }
  int ep = psc[t] - pair;            // exclusive pair base
  if (2 * t < NBLK)     c[2 * t]     = ep;
  if (2 * t + 1 < NBLK) c[2 * t + 1] = ep + v0;
  if (t == 0) c[NBLK] = psc[255];    // row total
}

// ---------------------------------------------------------------------------
// Multisplit P2: stable partition into bucket-major packed ebuf.
// Bucket bases recomputed redundantly: LDS scan of the 196 row totals.
// ebuf entries: (dst & 511) << 17 | src  (src < 131072).
// ---------------------------------------------------------------------------
__global__ __launch_bounds__(256) void partition_k(const int* __restrict__ counts,
                                                   const int* __restrict__ ei,
                                                   unsigned* __restrict__ ebuf,
                                                   int E, int NBLK, int NB1,
                                                   int NBUCK) {
  __shared__ uint2 slots[CHUNK];          // 32 KB
  __shared__ int scn[NBMAX], lcur[NBMAX], gadj[NBMAX];
  int t = threadIdx.x, blk = blockIdx.x;
  int e0 = blk * CHUNK;
  int n = min(CHUNK, E - e0);

  // bucket base: exclusive scan of row totals (register-held per thread t)
  int rowTot = (t < NBUCK) ? counts[t * NB1 + NBLK] : 0;
  scn[t] = rowTot;
  __syncthreads();
  for (int off = 1; off < 256; off <<= 1) {
    int add = (t >= off) ? scn[t - off] : 0;
    __syncthreads();
    scn[t] += add;
    __syncthreads();
  }
  int bucketBase = scn[t] - rowTot;       // exclusive
  __syncthreads();

  // per-bucket count & global base for this chunk
  int cnt = 0, base0 = 0;
  if (t < NBUCK) {
    int cpre  = counts[t * NB1 + blk];
    int cnext = counts[t * NB1 + blk + 1];   // col NBLK = total covers last
    cnt = cnext - cpre;
    base0 = bucketBase + cpre;
  }
  scn[t] = cnt;
  __syncthreads();
  for (int off = 1; off < 256; off <<= 1) {
    int add = (t >= off) ? scn[t - off] : 0;
    __syncthreads();
    scn[t] += add;
    __syncthreads();
  }
  int excl = scn[t] - cnt;
  if (t < NBUCK) { lcur[t] = excl; gadj[t] = base0 - excl; }
  __syncthreads();

  for (int i = t; i < n; i += 256) {
    int s = ei[e0 + i], d = ei[E + e0 + i];
    int pos = atomicAdd(&lcur[((unsigned)d) >> BSH], 1);
    slots[pos] = make_uint2((unsigned)s, (unsigned)d);
  }
  __syncthreads();
  for (int i = t; i < n; i += 256) {
    uint2 sd = slots[i];
    unsigned pk = ((sd.y & 511u) << 17) | sd.x;
    ebuf[gadj[sd.y >> BSH] + i] = pk;
  }
}

// ---------------------------------------------------------------------------
// Bucket-local CSR build: bucket base via redundant LDS scan of row totals;
// LDS-stage the bucket's packed edges; histogram + scan -> row_ptr; cursor
// fill. csr = plain src.
// ---------------------------------------------------------------------------
__global__ __launch_bounds__(BLD_T) void build_k(const unsigned* __restrict__ ebuf,
                                                 const int* __restrict__ counts,
                                                 int* __restrict__ row_ptr,
                                                 int* __restrict__ csr,
                                                 int N, int E, int NBLK, int NB1,
                                                 int NBUCK) {
  __shared__ int hist[512];
  __shared__ int psc[256];
  __shared__ int btot[NBMAX];
  __shared__ unsigned stg[BLD_CAP];       // 40 KB
  int t = threadIdx.x, b = blockIdx.x;
  int nodeBase = b << BSH;

  // inclusive scan of row totals -> S, T for this bucket
  if (t < 256) btot[t] = (t < NBUCK) ? counts[t * NB1 + NBLK] : 0;
  __syncthreads();
  for (int off = 1; off < 256; off <<= 1) {
    int add = (t >= off && t < 256) ? btot[t - off] : 0;
    __syncthreads();
    if (t < 256) btot[t] += add;
    __syncthreads();
  }
  int S = (b > 0) ? btot[b - 1] : 0;
  int T = btot[b];
  int n = T - S;
  bool useLds = (n <= BLD_CAP);
  __syncthreads();

  if (t < 512) hist[t] = 0;
  __syncthreads();
  for (int i = t; i < n; i += BLD_T) {
    unsigned v = ebuf[S + i];
    if (useLds) stg[i] = v;
    atomicAdd(&hist[v >> 17], 1);
  }
  __syncthreads();

  int v0 = 0, v1 = 0, pair = 0;
  if (t < 256) {
    v0 = hist[2 * t]; v1 = hist[2 * t + 1];
    pair = v0 + v1;
    psc[t] = pair;
  }
  __syncthreads();
  for (int off = 1; off < 256; off <<= 1) {
    int add = (t >= off && t < 256) ? psc[t - off] : 0;
    __syncthreads();
    if (t < 256) psc[t] += add;
    __syncthreads();
  }
  if (t < 256) {
    int ep = psc[t] - pair;
    int e0 = ep, e1 = ep + v0;
    int node0 = nodeBase + 2 * t;
    if (node0 < N) row_ptr[node0] = S + e0;
    if (node0 + 1 < N) row_ptr[node0 + 1] = S + e1;
    hist[2 * t] = e0; hist[2 * t + 1] = e1;   // reuse as cursors
  }
  if (b == 0 && t == 0) row_ptr[N] = E;
  __syncthreads();
  for (int i = t; i < n; i += BLD_T) {
    unsigned v = useLds ? stg[i] : ebuf[S + i];
    int pos = atomicAdd(&hist[v >> 17], 1);
    csr[S + pos] = (int)(v & 0x1FFFFu);
  }
}

// ===========================================================================
// Cooperative: agg1+bias1+relu+GEMM2 -> grid.sync -> agg2+bias2+log_softmax.
// Structure measured safe+fast in R2 (one grid.sync, ~73 µs). Phase A2 uses
// the 12 rows x 5 parts mapping (94% lane utilization on the 80-B live rows).
// ===========================================================================
__global__ __launch_bounds__(256, 4) void agg_k(
    const unsigned short* __restrict__ xw, const int* __restrict__ row_ptr,
    const int* __restrict__ csr, const float* __restrict__ b1,
    const unsigned short* __restrict__ w2s, const float* __restrict__ W2,
    unsigned short* __restrict__ hw, const float* __restrict__ b2,
    float* __restrict__ out, int N, int aggJobs1, int aggJobs2, int G) {
  __shared__ uint4 hsm[32][8];            // 4 KB, XOR-swizzled on part
  cg::grid_group grid = cg::this_grid();
  int t = threadIdx.x, blk = blockIdx.x;
  int wave = t >> 6, lane = t & 63;
  int part8 = lane & 7;

  // ---- phase A1: aggregation layer 1 + GEMM2 (32 rows per job) ----
  for (int j = blk; j < aggJobs1; j += G) {
    int blockRow0 = j * 32;
    int row = blockRow0 + wave * 8 + (lane >> 3);
    bool live = row < N;
    int start = live ? row_ptr[row] : 0;
    int end   = live ? row_ptr[row + 1] : 0;

    float acc[8], bcc[8];
#pragma unroll
    for (int q = 0; q < 8; ++q) { acc[q] = 0.f; bcc[q] = 0.f; }

    int i = start;
    for (; i + 3 < end; i += 4) {
      int s0 = csr[i];
      int s1 = csr[i + 1];
      int s2 = csr[i + 2];
      int s3 = csr[i + 3];
      uint4 v0 = *(const uint4*)(xw + ((size_t)s0 << 6) + (part8 << 3));
      uint4 v1 = *(const uint4*)(xw + ((size_t)s1 << 6) + (part8 << 3));
      uint4 v2 = *(const uint4*)(xw + ((size_t)s2 << 6) + (part8 << 3));
      uint4 v3 = *(const uint4*)(xw + ((size_t)s3 << 6) + (part8 << 3));
      acc[0] += bflo(v0.x); acc[1] += bfhi(v0.x);
      acc[2] += bflo(v0.y); acc[3] += bfhi(v0.y);
      acc[4] += bflo(v0.z); acc[5] += bfhi(v0.z);
      acc[6] += bflo(v0.w); acc[7] += bfhi(v0.w);
      bcc[0] += bflo(v1.x); bcc[1] += bfhi(v1.x);
      bcc[2] += bflo(v1.y); bcc[3] += bfhi(v1.y);
      bcc[4] += bflo(v1.z); bcc[5] += bfhi(v1.z);
      bcc[6] += bflo(v1.w); bcc[7] += bfhi(v1.w);
      acc[0] += bflo(v2.x); acc[1] += bfhi(v2.x);
      acc[2] += bflo(v2.y); acc[3] += bfhi(v2.y);
      acc[4] += bflo(v2.z); acc[5] += bfhi(v2.z);
      acc[6] += bflo(v2.w); acc[7] += bfhi(v2.w);
      bcc[0] += bflo(v3.x); bcc[1] += bfhi(v3.x);
      bcc[2] += bflo(v3.y); bcc[3] += bfhi(v3.y);
      bcc[4] += bflo(v3.z); bcc[5] += bfhi(v3.z);
      bcc[6] += bflo(v3.w); bcc[7] += bfhi(v3.w);
    }
    for (; i < end; ++i) {
      int s = csr[i];
      uint4 v = *(const uint4*)(xw + ((size_t)s << 6) + (part8 << 3));
      acc[0] += bflo(v.x); acc[1] += bfhi(v.x);
      acc[2] += bflo(v.y); acc[3] += bfhi(v.y);
      acc[4] += bflo(v.z); acc[5] += bfhi(v.z);
      acc[6] += bflo(v.w); acc[7] += bfhi(v.w);
    }

    if (live) {
      int c0 = part8 << 3;
      float4 bA = *(const float4*)(b1 + c0);
      float4 bB = *(const float4*)(b1 + c0 + 4);
      float r0 = fmaxf(acc[0] + bcc[0] + bA.x, 0.f);
      float r1 = fmaxf(acc[1] + bcc[1] + bA.y, 0.f);
      float r2 = fmaxf(acc[2] + bcc[2] + bA.z, 0.f);
      float r3 = fmaxf(acc[3] + bcc[3] + bA.w, 0.f);
      float r4 = fmaxf(acc[4] + bcc[4] + bB.x, 0.f);
      float r5 = fmaxf(acc[5] + bcc[5] + bB.y, 0.f);
      float r6 = fmaxf(acc[6] + bcc[6] + bB.z, 0.f);
      float r7 = fmaxf(acc[7] + bcc[7] + bB.w, 0.f);
      uint4 o = make_uint4(packbf(r0, r1), packbf(r2, r3),
                           packbf(r4, r5), packbf(r6, r7));
      int lr = row - blockRow0;
      hsm[lr][part8 ^ (lr & 7)] = o;
    }
    __syncthreads();

    // ---- GEMM2: h[32][64] @ W2[64][40] -> hw (stride 64, cols 0..39) ----
    if (wave < 2) {
      int frow0 = blockRow0 + wave * 16;
      if (frow0 < N) {
        int m = lane & 15, q = lane >> 4;
        if (frow0 + 16 <= N) {
          short8 b[6];
#pragma unroll
          for (int f = 0; f < 6; ++f)
            b[f] = *(const short8*)(w2s + f * 512 + lane * 8);
          short8 a[2];
#pragma unroll
          for (int ks = 0; ks < 2; ++ks) {
            int lr = wave * 16 + m;
            int pp = ks * 4 + q;
            a[ks] = *(const short8*)&hsm[lr][pp ^ (lr & 7)];
          }
          f32x4 z = {0.f, 0.f, 0.f, 0.f};
          f32x4 acc2[3] = {z, z, z};
#pragma unroll
          for (int ct = 0; ct < 3; ++ct)
#pragma unroll
            for (int ks = 0; ks < 2; ++ks)
              acc2[ct] = __builtin_amdgcn_mfma_f32_16x16x32_bf16(
                  a[ks], b[ct * 2 + ks], acc2[ct], 0, 0, 0);
#pragma unroll
          for (int ct = 0; ct < 3; ++ct)
#pragma unroll
            for (int r = 0; r < 4; ++r) {
              int row2 = frow0 + q * 4 + r;
              int c = ct * 16 + m;
              if (c < F_OUT) hw[(size_t)row2 * F_HID + c] = f2bf(acc2[ct][r]);
            }
        } else {
          for (int r = 0; r < 16; ++r) {          // tail rows (N%16 != 0)
            int row2 = frow0 + r;
            if (row2 >= N) break;
            if (lane < F_OUT) {
              int lr = wave * 16 + r;
              float s = 0.f;
              for (int k = 0; k < F_HID; ++k) {
                const unsigned short* hp =
                    (const unsigned short*)&hsm[lr][(k >> 3) ^ (lr & 7)];
                s = fmaf(bf2f(hp[k & 7]), W2[k * F_OUT + lane], s);
              }
              hw[(size_t)row2 * F_HID + lane] = f2bf(s);
            }
          }
        }
      }
    }
    __syncthreads();   // protect hsm before next job
  }
  grid.sync();

  // ---- phase A2: aggregation layer 2 + bias2 + log_softmax (12 x 5) ----
  int grp = lane / 5;                      // 12 groups; lanes 60..63 idle
  int part = lane - grp * 5;
  for (int j = blk; j < aggJobs2; j += G) {
    int row = j * 48 + wave * 12 + grp;
    bool live = (grp < 12) && (row < N);

    int start = live ? row_ptr[row] : 0;
    int end   = live ? row_ptr[row + 1] : 0;

    float acc[8], bcc[8];
#pragma unroll
    for (int q = 0; q < 8; ++q) { acc[q] = 0.f; bcc[q] = 0.f; }

    int i = start;
    for (; i + 3 < end; i += 4) {
      int s0 = csr[i];
      int s1 = csr[i + 1];
      int s2 = csr[i + 2];
      int s3 = csr[i + 3];
      uint4 v0 = *(const uint4*)(hw + ((size_t)s0 << 6) + (part << 3));
      uint4 v1 = *(const uint4*)(hw + ((size_t)s1 << 6) + (part << 3));
      uint4 v2 = *(const uint4*)(hw + ((size_t)s2 << 6) + (part << 3));
      uint4 v3 = *(const uint4*)(hw + ((size_t)s3 << 6) + (part << 3));
      acc[0] += bflo(v0.x); acc[1] += bfhi(v0.x);
      acc[2] += bflo(v0.y); acc[3] += bfhi(v0.y);
      acc[4] += bflo(v0.z); acc[5] += bfhi(v0.z);
      acc[6] += bflo(v0.w); acc[7] += bfhi(v0.w);
      bcc[0] += bflo(v1.x); bcc[1] += bfhi(v1.x);
      bcc[2] += bflo(v1.y); bcc[3] += bfhi(v1.y);
      bcc[4] += bflo(v1.z); bcc[5] += bfhi(v1.z);
      bcc[6] += bflo(v1.w); bcc[7] += bfhi(v1.w);
      acc[0] += bflo(v2.x); acc[1] += bfhi(v2.x);
      acc[2] += bflo(v2.y); acc[3] += bfhi(v2.y);
      acc[4] += bflo(v2.z); acc[5] += bfhi(v2.z);
      acc[6] += bflo(v2.w); acc[7] += bfhi(v2.w);
      bcc[0] += bflo(v3.x); bcc[1] += bfhi(v3.x);
      bcc[2] += bflo(v3.y); bcc[3] += bfhi(v3.y);
      bcc[4] += bflo(v3.z); bcc[5] += bfhi(v3.z);
      bcc[6] += bflo(v3.w); bcc[7] += bfhi(v3.w);
    }
    for (; i < end; ++i) {
      int s = csr[i];
      uint4 v = *(const uint4*)(hw + ((size_t)s << 6) + (part << 3));
      acc[0] += bflo(v.x); acc[1] += bfhi(v.x);
      acc[2] += bflo(v.y); acc[3] += bfhi(v.y);
      acc[4] += bflo(v.z); acc[5] += bfhi(v.z);
      acc[6] += bflo(v.w); acc[7] += bfhi(v.w);
    }

    float vj[8];
    float mx = -3.4e38f;
    if (live) {
      int c0 = part << 3;
      float4 bA = *(const float4*)(b2 + c0);
      float4 bB = *(const float4*)(b2 + c0 + 4);
      vj[0] = acc[0] + bcc[0] + bA.x; vj[1] = acc[1] + bcc[1] + bA.y;
      vj[2] = acc[2] + bcc[2] + bA.z; vj[3] = acc[3] + bcc[3] + bA.w;
      vj[4] = acc[4] + bcc[4] + bB.x; vj[5] = acc[5] + bcc[5] + bB.y;
      vj[6] = acc[6] + bcc[6] + bB.z; vj[7] = acc[7] + bcc[7] + bB.w;
#pragma unroll
      for (int q = 0; q < 8; ++q) mx = fmaxf(mx, vj[q]);
    }
    int g0 = (grp < 12 ? grp : 0) * 5;
    float mxAll = mx;
#pragma unroll
    for (int q = 0; q < 5; ++q) mxAll = fmaxf(mxAll, __shfl(mx, g0 + q, 64));
    float ex = 0.f;
    if (live) {
#pragma unroll
      for (int q = 0; q < 8; ++q) ex += __expf(vj[q] - mxAll);
    }
    float exAll = 0.f;
#pragma unroll
    for (int q = 0; q < 5; ++q) exAll += __shfl(ex, g0 + q, 64);
    float lse = __logf(exAll) + mxAll;

    if (live) {
      int c0 = part << 3;
      float* op = out + (size_t)row * F_OUT + c0;
      *(float4*)op = make_float4(vj[0] - lse, vj[1] - lse,
                                 vj[2] - lse, vj[3] - lse);
      *(float4*)(op + 4) = make_float4(vj[4] - lse, vj[5] - lse,
                                       vj[6] - lse, vj[7] - lse);
    }
  }
}

// ---------------------------------------------------------------------------
// ws layout (≈33 MB):
//   regA : xw[N,64] bf16
//   regB : ebuf[E] u32 — reused as hw[N,64] bf16 (ebuf dead after build)
//   row_ptr : N+1 | csr : E | counts : NBUCK*(NBLK+1) | w2s : 3072
// ---------------------------------------------------------------------------
extern "C" void kernel_launch(void* const* d_in, const int* in_sizes, int n_in,
                              void* d_out, int out_size, void* d_ws, size_t ws_size,
                              hipStream_t stream) {
  const float* x  = (const float*)d_in[0];
  const int*   ei = (const int*)d_in[1];
  const float* W1 = (const float*)d_in[2];
  const float* b1 = (const float*)d_in[3];
  const float* W2 = (const float*)d_in[4];
  const float* b2 = (const float*)d_in[5];

  int N = in_sizes[0] / F_IN;
  int E = in_sizes[1] / 2;

  char* base = (char*)d_ws;
  size_t szA = (size_t)N * F_HID * sizeof(unsigned short);
  size_t szEb = (size_t)E * sizeof(unsigned);
  size_t szHw = (size_t)N * F_HID * sizeof(unsigned short);
  size_t szB = (szEb > szHw) ? szEb : szHw;
  unsigned short* xw = (unsigned short*)base;
  char* regB = base + ((szA + 255) & ~(size_t)255);
  unsigned* ebuf       = (unsigned*)regB;
  unsigned short* hw   = (unsigned short*)regB;
  int* row_ptr = (int*)(regB + ((szB + 255) & ~(size_t)255));
  int* csr     = row_ptr + N + 1;
  int* counts  = csr + E;
  float* out = (float*)d_out;

  int NBLK  = (E + CHUNK - 1) / CHUNK;
  int NB1   = NBLK + 1;
  int NBUCK = (N + 511) >> BSH;
  unsigned short* w2s =
      (unsigned short*)(((uintptr_t)(counts + NBUCK * NB1) + 63) & ~(uintptr_t)63);
  int gemmGrid = (N + 63) / 64;
  int aggJobs1 = (N + 31) / 32;      // phase A1: 32 rows per job
  int aggJobs2 = (N + 47) / 48;      // phase A2: 48 rows per job (12/wave)

  // fused: pcount + w2s (blocks 0..NBLK-1) + gemm1 (remaining blocks)
  front_k<<<NBLK + gemmGrid, 256, 0, stream>>>(x, W1, W2, w2s, xw, N,
                                               ei, counts, E, NBLK, NB1, NBUCK);

  scanR_k<<<NBUCK, 256, 0, stream>>>(counts, NBLK, NB1);
  partition_k<<<NBLK, 256, 0, stream>>>(counts, ei, ebuf, E, NBLK, NB1, NBUCK);
  build_k<<<NBUCK, BLD_T, 0, stream>>>(ebuf, counts, row_ptr, csr,
                                       N, E, NBLK, NB1, NBUCK);

  // cooperative agg (structure measured safe at ~73 µs in R2: one grid.sync)
  static int cap = -1, ncu = 0;
  if (cap < 0) {
    hipDeviceProp_t prop;
    int dev = 0;
    (void)hipGetDevice(&dev);
    (void)hipGetDeviceProperties(&prop, dev);
    ncu = prop.multiProcessorCount;
    if (ncu <= 0) ncu = 256;
    if (hipOccupancyMaxActiveBlocksPerMultiprocessor(&cap,
            reinterpret_cast<const void*>(agg_k), 256, 0) != hipSuccess ||
        cap < 1)
      cap = 4;
  }
  int G = cap * ncu;
  int maxJobs = (aggJobs1 > aggJobs2) ? aggJobs1 : aggJobs2;
  if (G > maxJobs) G = maxJobs;

  void* a2[] = {(void*)&xw, (void*)&row_ptr, (void*)&csr, (void*)&b1,
                (void*)&w2s, (void*)&W2, (void*)&hw, (void*)&b2,
                (void*)&out, (void*)&N, (void*)&aggJobs1, (void*)&aggJobs2,
                (void*)&G};
  (void)hipLaunchCooperativeKernel(reinterpret_cast<const void*>(agg_k),
                                   dim3(G), dim3(256), a2, 0, stream);
}

// Round 7
// 212.330 us; speedup vs baseline: 5.4357x; 1.5366x over previous
//
#include <hip/hip_runtime.h>
#include <cstdint>
#include <cstddef>

#define F_IN  128
#define F_HID 64
#define F_OUT 40

#define BSH   9     // bucket = dst >> 9 (512 nodes/bucket)
#define NBMAX 256   // supports N <= 131072
#define CHUNK 4096  // edges per partition block

#define BLD_T   512   // build_k threads
#define BLD_CAP 10240 // LDS-staged edges per bucket (40 KB)

typedef __attribute__((ext_vector_type(8))) short short8;   // 8 bf16 = 4 VGPR
typedef __attribute__((ext_vector_type(4))) float f32x4;    // MFMA C/D

// bf16 <-> f32 helpers (RNE on pack; values are finite)
__device__ __forceinline__ unsigned short f2bf(float f) {
  unsigned u = __float_as_uint(f);
  u += 0x7fffu + ((u >> 16) & 1u);
  return (unsigned short)(u >> 16);
}
__device__ __forceinline__ float bf2f(unsigned short b) {
  return __uint_as_float((unsigned)b << 16);
}
__device__ __forceinline__ float bflo(unsigned u) { return __uint_as_float(u << 16); }
__device__ __forceinline__ float bfhi(unsigned u) { return __uint_as_float(u & 0xffff0000u); }
__device__ __forceinline__ unsigned packbf(float lo, float hi) {
  return (unsigned)f2bf(lo) | ((unsigned)f2bf(hi) << 16);
}

// ---------------------------------------------------------------------------
// FRONT (fused): blocks [0,NBLK) run pcount (block 0 additionally emits the
// w2s MFMA-swizzled copy of W2); blocks [NBLK,+gemmBlks) run MFMA GEMM1,
// each converting W1 into a 16 KB LDS B-fragment copy first.
// counts layout: [NBUCK][NB1] with NB1 = NBLK+1 (col NBLK = row totals,
// filled by scanR_k).
// ---------------------------------------------------------------------------
__global__ __launch_bounds__(256) void front_k(const float* __restrict__ x,
                                               const float* __restrict__ W1,
                                               const float* __restrict__ W2,
                                               unsigned short* __restrict__ w2s,
                                               unsigned short* __restrict__ xw, int N,
                                               const int* __restrict__ ei,
                                               int* __restrict__ counts,
                                               int E, int NBLK, int NB1, int NBUCK) {
  __shared__ int lh[NBMAX];
  __shared__ unsigned short w1l[8192];    // 16 KB swizzled W1 (gemm1 branch)
  int t = threadIdx.x;

  if ((int)blockIdx.x < NBLK) {
    // ---- pcount ----
    int blk = blockIdx.x;
    lh[t] = 0;
    __syncthreads();
    int e0 = blk * CHUNK;
    int n = min(CHUNK, E - e0);
    for (int i = t; i < n; i += 256)
      atomicAdd(&lh[((unsigned)ei[E + e0 + i]) >> BSH], 1);
    __syncthreads();
    if (t < NBUCK) counts[t * NB1 + blk] = lh[t];
    if (blk == 0) {
      // emit swizzled W2 (cols >= 40 zero) for GEMM2
      for (int i = t; i < 3072; i += 256) {
        int f = i >> 9, r = i & 511;
        int lane = r >> 3, jj = r & 7;
        int ct = f >> 1, ks = f & 1;
        int n2 = ct * 16 + (lane & 15);
        int k = ks * 32 + (lane >> 4) * 8 + jj;
        w2s[i] = (n2 < F_OUT) ? f2bf(W2[k * F_OUT + n2]) : (unsigned short)0;
      }
    }
    return;
  }

  // ---- gemm1: convert W1 -> LDS (all threads, coalesced global reads) ----
  {
    int k = t >> 1, n0 = (t & 1) * 32;       // thread owns W1[k][n0..n0+32)
    const float4* wp = (const float4*)(W1 + k * F_HID + n0);
    float4 v[8];
#pragma unroll
    for (int u = 0; u < 8; ++u) v[u] = wp[u];
#pragma unroll
    for (int u = 0; u < 32; ++u) {
      int n = n0 + u;
      float f = ((const float*)v)[u];
      int idx = ((n >> 4) * 4 + (k >> 5)) * 512 +
                (((k >> 3) & 3) * 16 + (n & 15)) * 8 + (k & 7);
      w1l[idx] = f2bf(f);
    }
  }
  __syncthreads();

  int gblk = blockIdx.x - NBLK;
  int lane = t & 63;
  int wid  = gblk * 4 + (t >> 6);
  int row0 = wid * 16;
  if (row0 >= N) return;
  int m = lane & 15, q = lane >> 4;

  if (row0 + 16 <= N) {
    short8 b[16];
#pragma unroll
    for (int f = 0; f < 16; ++f)
      b[f] = *(const short8*)(w1l + f * 512 + lane * 8);

    short8 a[4];
#pragma unroll
    for (int ks = 0; ks < 4; ++ks) {
      const float* xp = x + (size_t)(row0 + m) * F_IN + ks * 32 + q * 8;
      float4 v0 = *(const float4*)xp;
      float4 v1 = *(const float4*)(xp + 4);
      short8 tt;
      tt[0] = (short)f2bf(v0.x); tt[1] = (short)f2bf(v0.y);
      tt[2] = (short)f2bf(v0.z); tt[3] = (short)f2bf(v0.w);
      tt[4] = (short)f2bf(v1.x); tt[5] = (short)f2bf(v1.y);
      tt[6] = (short)f2bf(v1.z); tt[7] = (short)f2bf(v1.w);
      a[ks] = tt;
    }

    f32x4 z = {0.f, 0.f, 0.f, 0.f};
    f32x4 acc[4] = {z, z, z, z};
#pragma unroll
    for (int ct = 0; ct < 4; ++ct)
#pragma unroll
      for (int ks = 0; ks < 4; ++ks)
        acc[ct] = __builtin_amdgcn_mfma_f32_16x16x32_bf16(a[ks], b[ct * 4 + ks],
                                                          acc[ct], 0, 0, 0);
#pragma unroll
    for (int ct = 0; ct < 4; ++ct)
#pragma unroll
      for (int r = 0; r < 4; ++r) {
        int row = row0 + q * 4 + r;                 // D: col=lane&15, row=q*4+reg
        xw[(size_t)row * F_HID + ct * 16 + m] = f2bf(acc[ct][r]);
      }
  } else {
    for (int r = 0; r < 16 && row0 + r < N; ++r) { // tail: col = lane
      const float* xr = x + (size_t)(row0 + r) * F_IN;
      float s = 0.f;
      for (int k = 0; k < F_IN; ++k) s = fmaf(xr[k], W1[k * F_HID + lane], s);
      xw[(size_t)(row0 + r) * F_HID + lane] = f2bf(s);
    }
  }
}

// ---------------------------------------------------------------------------
// Row-wise exclusive scan: block b scans counts[b][0..NBLK) in place and
// writes the row total to counts[b][NBLK]. 196 parallel blocks.
// ---------------------------------------------------------------------------
__global__ __launch_bounds__(256) void scanR_k(int* __restrict__ counts,
                                               int NBLK, int NB1) {
  __shared__ int sm[512];
  __shared__ int psc[256];
  int t = threadIdx.x;
  int* c = counts + blockIdx.x * NB1;

  sm[t]       = (t < NBLK)       ? c[t]       : 0;
  sm[t + 256] = (t + 256 < NBLK) ? c[t + 256] : 0;
  __syncthreads();

  int v0 = sm[2 * t], v1 = sm[2 * t + 1];
  int pair = v0 + v1;
  psc[t] = pair;
  __syncthreads();
  for (int off = 1; off < 256; off <<= 1) {
    int add = (t >= off) ? psc[t - off] : 0;
    __syncthreads();
    psc[t] += add;
    __syncthreads();
  }
  int ep = psc[t] - pair;            // exclusive pair base
  if (2 * t < NBLK)     c[2 * t]     = ep;
  if (2 * t + 1 < NBLK) c[2 * t + 1] = ep + v0;
  if (t == 0) c[NBLK] = psc[255];    // row total
}

// ---------------------------------------------------------------------------
// Multisplit P2: stable partition into bucket-major packed ebuf.
// Bucket bases recomputed redundantly: LDS scan of the row totals.
// ebuf entries: (dst & 511) << 17 | src  (src < 131072).
// ---------------------------------------------------------------------------
__global__ __launch_bounds__(256) void partition_k(const int* __restrict__ counts,
                                                   const int* __restrict__ ei,
                                                   unsigned* __restrict__ ebuf,
                                                   int E, int NBLK, int NB1,
                                                   int NBUCK) {
  __shared__ uint2 slots[CHUNK];          // 32 KB
  __shared__ int scn[NBMAX], lcur[NBMAX], gadj[NBMAX];
  int t = threadIdx.x, blk = blockIdx.x;
  int e0 = blk * CHUNK;
  int n = min(CHUNK, E - e0);

  // bucket base: exclusive scan of row totals
  int rowTot = (t < NBUCK) ? counts[t * NB1 + NBLK] : 0;
  scn[t] = rowTot;
  __syncthreads();
  for (int off = 1; off < 256; off <<= 1) {
    int add = (t >= off) ? scn[t - off] : 0;
    __syncthreads();
    scn[t] += add;
    __syncthreads();
  }
  int bucketBase = scn[t] - rowTot;       // exclusive
  __syncthreads();

  // per-bucket count & global base for this chunk
  int cnt = 0, base0 = 0;
  if (t < NBUCK) {
    int cpre  = counts[t * NB1 + blk];
    int cnext = counts[t * NB1 + blk + 1];
    cnt = cnext - cpre;
    base0 = bucketBase + cpre;
  }
  scn[t] = cnt;
  __syncthreads();
  for (int off = 1; off < 256; off <<= 1) {
    int add = (t >= off) ? scn[t - off] : 0;
    __syncthreads();
    scn[t] += add;
    __syncthreads();
  }
  int excl = scn[t] - cnt;
  if (t < NBUCK) { lcur[t] = excl; gadj[t] = base0 - excl; }
  __syncthreads();

  for (int i = t; i < n; i += 256) {
    int s = ei[e0 + i], d = ei[E + e0 + i];
    int pos = atomicAdd(&lcur[((unsigned)d) >> BSH], 1);
    slots[pos] = make_uint2((unsigned)s, (unsigned)d);
  }
  __syncthreads();
  for (int i = t; i < n; i += 256) {
    uint2 sd = slots[i];
    unsigned pk = ((sd.y & 511u) << 17) | sd.x;
    ebuf[gadj[sd.y >> BSH] + i] = pk;
  }
}

// ---------------------------------------------------------------------------
// Bucket-local CSR build: bucket base via redundant LDS scan of row totals;
// LDS-stage the bucket's packed edges; histogram + scan -> row_ptr; cursor
// fill. csr = plain src.
// ---------------------------------------------------------------------------
__global__ __launch_bounds__(BLD_T) void build_k(const unsigned* __restrict__ ebuf,
                                                 const int* __restrict__ counts,
                                                 int* __restrict__ row_ptr,
                                                 int* __restrict__ csr,
                                                 int N, int E, int NBLK, int NB1,
                                                 int NBUCK) {
  __shared__ int hist[512];
  __shared__ int psc[256];
  __shared__ int btot[NBMAX];
  __shared__ unsigned stg[BLD_CAP];       // 40 KB
  int t = threadIdx.x, b = blockIdx.x;
  int nodeBase = b << BSH;

  // inclusive scan of row totals -> S, T for this bucket
  if (t < 256) btot[t] = (t < NBUCK) ? counts[t * NB1 + NBLK] : 0;
  __syncthreads();
  for (int off = 1; off < 256; off <<= 1) {
    int add = (t >= off && t < 256) ? btot[t - off] : 0;
    __syncthreads();
    if (t < 256) btot[t] += add;
    __syncthreads();
  }
  int S = (b > 0) ? btot[b - 1] : 0;
  int T = btot[b];
  int n = T - S;
  bool useLds = (n <= BLD_CAP);
  __syncthreads();

  if (t < 512) hist[t] = 0;
  __syncthreads();
  for (int i = t; i < n; i += BLD_T) {
    unsigned v = ebuf[S + i];
    if (useLds) stg[i] = v;
    atomicAdd(&hist[v >> 17], 1);
  }
  __syncthreads();

  int v0 = 0, v1 = 0, pair = 0;
  if (t < 256) {
    v0 = hist[2 * t]; v1 = hist[2 * t + 1];
    pair = v0 + v1;
    psc[t] = pair;
  }
  __syncthreads();
  for (int off = 1; off < 256; off <<= 1) {
    int add = (t >= off && t < 256) ? psc[t - off] : 0;
    __syncthreads();
    if (t < 256) psc[t] += add;
    __syncthreads();
  }
  if (t < 256) {
    int ep = psc[t] - pair;
    int e0 = ep, e1 = ep + v0;
    int node0 = nodeBase + 2 * t;
    if (node0 < N) row_ptr[node0] = S + e0;
    if (node0 + 1 < N) row_ptr[node0 + 1] = S + e1;
    hist[2 * t] = e0; hist[2 * t + 1] = e1;   // reuse as cursors
  }
  if (b == 0 && t == 0) row_ptr[N] = E;
  __syncthreads();
  for (int i = t; i < n; i += BLD_T) {
    unsigned v = useLds ? stg[i] : ebuf[S + i];
    int pos = atomicAdd(&hist[v >> 17], 1);
    csr[S + pos] = (int)(v & 0x1FFFFu);
  }
}

// ---------------------------------------------------------------------------
// 8-wide gather macro bodies (latency-bound gathers -> 8 outstanding
// dwordx4 loads per lane before the accumulate chain waits).
// ---------------------------------------------------------------------------
#define GATHER8(SRC, STRIDE_SH)                                              \
  for (; i + 7 < end; i += 8) {                                              \
    int s0 = csr[i],     s1 = csr[i + 1], s2 = csr[i + 2], s3 = csr[i + 3];  \
    int s4 = csr[i + 4], s5 = csr[i + 5], s6 = csr[i + 6], s7 = csr[i + 7];  \
    uint4 v0 = *(const uint4*)(SRC + ((size_t)s0 << STRIDE_SH) + (part << 3)); \
    uint4 v1 = *(const uint4*)(SRC + ((size_t)s1 << STRIDE_SH) + (part << 3)); \
    uint4 v2 = *(const uint4*)(SRC + ((size_t)s2 << STRIDE_SH) + (part << 3)); \
    uint4 v3 = *(const uint4*)(SRC + ((size_t)s3 << STRIDE_SH) + (part << 3)); \
    uint4 v4 = *(const uint4*)(SRC + ((size_t)s4 << STRIDE_SH) + (part << 3)); \
    uint4 v5 = *(const uint4*)(SRC + ((size_t)s5 << STRIDE_SH) + (part << 3)); \
    uint4 v6 = *(const uint4*)(SRC + ((size_t)s6 << STRIDE_SH) + (part << 3)); \
    uint4 v7 = *(const uint4*)(SRC + ((size_t)s7 << STRIDE_SH) + (part << 3)); \
    ACC8(acc, v0); ACC8(bcc, v1); ACC8(acc, v2); ACC8(bcc, v3);              \
    ACC8(acc, v4); ACC8(bcc, v5); ACC8(acc, v6); ACC8(bcc, v7);              \
  }                                                                          \
  for (; i < end; ++i) {                                                     \
    int s = csr[i];                                                          \
    uint4 v = *(const uint4*)(SRC + ((size_t)s << STRIDE_SH) + (part << 3)); \
    ACC8(acc, v);                                                            \
  }

#define ACC8(A, V)                                                           \
  A[0] += bflo(V.x); A[1] += bfhi(V.x); A[2] += bflo(V.y); A[3] += bfhi(V.y);\
  A[4] += bflo(V.z); A[5] += bfhi(V.z); A[6] += bflo(V.w); A[7] += bfhi(V.w);

// ---------------------------------------------------------------------------
// FUSED aggregation-1 + bias1 + ReLU + GEMM2 (row-parallel, lane-private).
// Wave = 8 rows (lane: row=lane>>3, part=lane&7 owning 8 cols = 16 B).
// 8-wide unrolled gather. h[32][64] staged in XOR-swizzled LDS; waves 0/1
// run the 64x40 MFMA GEMM -> hw[N][64] bf16 (cols 0..39, 128-B rows).
// ---------------------------------------------------------------------------
__global__ __launch_bounds__(256) void agg1g2_k(const unsigned short* __restrict__ xw,
                                                const int* __restrict__ row_ptr,
                                                const int* __restrict__ csr,
                                                const float* __restrict__ b1,
                                                const unsigned short* __restrict__ w2s,
                                                const float* __restrict__ W2,
                                                unsigned short* __restrict__ hw, int N) {
  __shared__ uint4 hsm[32][8];            // 4 KB, XOR-swizzled on part
  int t = threadIdx.x;
  int wave = t >> 6, lane = t & 63;
  int blockRow0 = blockIdx.x * 32;
  int row = blockRow0 + wave * 8 + (lane >> 3);
  int part = lane & 7;
  bool live = row < N;

  int start = live ? row_ptr[row] : 0;
  int end   = live ? row_ptr[row + 1] : 0;

  float acc[8], bcc[8];
#pragma unroll
  for (int j = 0; j < 8; ++j) { acc[j] = 0.f; bcc[j] = 0.f; }

  int i = start;
  GATHER8(xw, 6)

  if (live) {
    int c0 = part << 3;
    float4 bA = *(const float4*)(b1 + c0);
    float4 bB = *(const float4*)(b1 + c0 + 4);
    float r0 = fmaxf(acc[0] + bcc[0] + bA.x, 0.f);
    float r1 = fmaxf(acc[1] + bcc[1] + bA.y, 0.f);
    float r2 = fmaxf(acc[2] + bcc[2] + bA.z, 0.f);
    float r3 = fmaxf(acc[3] + bcc[3] + bA.w, 0.f);
    float r4 = fmaxf(acc[4] + bcc[4] + bB.x, 0.f);
    float r5 = fmaxf(acc[5] + bcc[5] + bB.y, 0.f);
    float r6 = fmaxf(acc[6] + bcc[6] + bB.z, 0.f);
    float r7 = fmaxf(acc[7] + bcc[7] + bB.w, 0.f);
    uint4 o = make_uint4(packbf(r0, r1), packbf(r2, r3),
                         packbf(r4, r5), packbf(r6, r7));
    int lr = row - blockRow0;
    hsm[lr][part ^ (lr & 7)] = o;
  }
  __syncthreads();

  // ---- GEMM2: h[32][64] @ W2[64][40] -> hw (stride 64, cols 0..39) ----
  if (wave < 2) {
    int frow0 = blockRow0 + wave * 16;
    if (frow0 >= N) return;
    int m = lane & 15, q = lane >> 4;
    if (frow0 + 16 <= N) {
      short8 b[6];
#pragma unroll
      for (int f = 0; f < 6; ++f)
        b[f] = *(const short8*)(w2s + f * 512 + lane * 8);
      short8 a[2];
#pragma unroll
      for (int ks = 0; ks < 2; ++ks) {
        int lr = wave * 16 + m;
        int pp = ks * 4 + q;
        a[ks] = *(const short8*)&hsm[lr][pp ^ (lr & 7)];
      }
      f32x4 z = {0.f, 0.f, 0.f, 0.f};
      f32x4 acc2[3] = {z, z, z};
#pragma unroll
      for (int ct = 0; ct < 3; ++ct)
#pragma unroll
        for (int ks = 0; ks < 2; ++ks)
          acc2[ct] = __builtin_amdgcn_mfma_f32_16x16x32_bf16(
              a[ks], b[ct * 2 + ks], acc2[ct], 0, 0, 0);
#pragma unroll
      for (int ct = 0; ct < 3; ++ct)
#pragma unroll
        for (int r = 0; r < 4; ++r) {
          int row2 = frow0 + q * 4 + r;
          int c = ct * 16 + m;
          if (c < F_OUT) hw[(size_t)row2 * F_HID + c] = f2bf(acc2[ct][r]);
        }
    } else {
      for (int r = 0; r < 16; ++r) {            // tail rows (N%16 != 0)
        int row2 = frow0 + r;
        if (row2 >= N) break;
        if (lane < F_OUT) {
          int lr = wave * 16 + r;
          float s = 0.f;
          for (int k = 0; k < F_HID; ++k) {
            const unsigned short* hp =
                (const unsigned short*)&hsm[lr][(k >> 3) ^ (lr & 7)];
            s = fmaf(bf2f(hp[k & 7]), W2[k * F_OUT + lane], s);
          }
          hw[(size_t)row2 * F_HID + lane] = f2bf(s);
        }
      }
    }
  }
}

// ---------------------------------------------------------------------------
// Aggregation layer 2 + bias2 + log_softmax — 12 rows x 5 parts per wave,
// 8-wide unrolled gather. Softmax reduces across the 5-lane group via shfl.
// ---------------------------------------------------------------------------
__global__ __launch_bounds__(256) void agg2_ls_k(const unsigned short* __restrict__ hw,
                                                 const int* __restrict__ row_ptr,
                                                 const int* __restrict__ csr,
                                                 const float* __restrict__ b2,
                                                 float* __restrict__ out, int N) {
  int t = threadIdx.x;
  int wave = t >> 6, lane = t & 63;
  int grp = lane / 5;                      // 12 groups; lanes 60..63 idle
  int part = lane - grp * 5;
  int row = blockIdx.x * 48 + wave * 12 + grp;
  bool live = (grp < 12) && (row < N);

  int start = live ? row_ptr[row] : 0;
  int end   = live ? row_ptr[row + 1] : 0;

  float acc[8], bcc[8];
#pragma unroll
  for (int j = 0; j < 8; ++j) { acc[j] = 0.f; bcc[j] = 0.f; }

  int i = start;
  GATHER8(hw, 6)

  float vj[8];
  float mx = -3.4e38f;
  if (live) {
    int c0 = part << 3;
    float4 bA = *(const float4*)(b2 + c0);
    float4 bB = *(const float4*)(b2 + c0 + 4);
    vj[0] = acc[0] + bcc[0] + bA.x; vj[1] = acc[1] + bcc[1] + bA.y;
    vj[2] = acc[2] + bcc[2] + bA.z; vj[3] = acc[3] + bcc[3] + bA.w;
    vj[4] = acc[4] + bcc[4] + bB.x; vj[5] = acc[5] + bcc[5] + bB.y;
    vj[6] = acc[6] + bcc[6] + bB.z; vj[7] = acc[7] + bcc[7] + bB.w;
#pragma unroll
    for (int q = 0; q < 8; ++q) mx = fmaxf(mx, vj[q]);
  }
  int g0 = (grp < 12 ? grp : 0) * 5;
  float mxAll = mx;
#pragma unroll
  for (int q = 0; q < 5; ++q) mxAll = fmaxf(mxAll, __shfl(mx, g0 + q, 64));
  float ex = 0.f;
  if (live) {
#pragma unroll
    for (int q = 0; q < 8; ++q) ex += __expf(vj[q] - mxAll);
  }
  float exAll = 0.f;
#pragma unroll
  for (int q = 0; q < 5; ++q) exAll += __shfl(ex, g0 + q, 64);
  float lse = __logf(exAll) + mxAll;

  if (live) {
    int c0 = part << 3;
    float* op = out + (size_t)row * F_OUT + c0;
    *(float4*)op = make_float4(vj[0] - lse, vj[1] - lse, vj[2] - lse, vj[3] - lse);
    *(float4*)(op + 4) = make_float4(vj[4] - lse, vj[5] - lse, vj[6] - lse, vj[7] - lse);
  }
}

// ---------------------------------------------------------------------------
// ws layout (≈33 MB):
//   regA : xw[N,64] bf16
//   regB : ebuf[E] u32 — reused as hw[N,64] bf16 (ebuf dead after build)
//   row_ptr : N+1 | csr : E | counts : NBUCK*(NBLK+1) | w2s : 3072
// ---------------------------------------------------------------------------
extern "C" void kernel_launch(void* const* d_in, const int* in_sizes, int n_in,
                              void* d_out, int out_size, void* d_ws, size_t ws_size,
                              hipStream_t stream) {
  const float* x  = (const float*)d_in[0];
  const int*   ei = (const int*)d_in[1];
  const float* W1 = (const float*)d_in[2];
  const float* b1 = (const float*)d_in[3];
  const float* W2 = (const float*)d_in[4];
  const float* b2 = (const float*)d_in[5];

  int N = in_sizes[0] / F_IN;
  int E = in_sizes[1] / 2;

  char* base = (char*)d_ws;
  size_t szA = (size_t)N * F_HID * sizeof(unsigned short);
  size_t szEb = (size_t)E * sizeof(unsigned);
  size_t szHw = (size_t)N * F_HID * sizeof(unsigned short);
  size_t szB = (szEb > szHw) ? szEb : szHw;
  unsigned short* xw = (unsigned short*)base;
  char* regB = base + ((szA + 255) & ~(size_t)255);
  unsigned* ebuf       = (unsigned*)regB;
  unsigned short* hw   = (unsigned short*)regB;
  int* row_ptr = (int*)(regB + ((szB + 255) & ~(size_t)255));
  int* csr     = row_ptr + N + 1;
  int* counts  = csr + E;
  float* out = (float*)d_out;

  int NBLK  = (E + CHUNK - 1) / CHUNK;
  int NB1   = NBLK + 1;
  int NBUCK = (N + 511) >> BSH;
  unsigned short* w2s =
      (unsigned short*)(((uintptr_t)(counts + NBUCK * NB1) + 63) & ~(uintptr_t)63);
  int gemmGrid = (N + 63) / 64;
  int aggGrid1 = (N + 31) / 32;      // agg1g2: 32 rows per block
  int aggGrid2 = (N + 47) / 48;      // agg2: 48 rows per block (12/wave)

  // fused: pcount + w2s (blocks 0..NBLK-1) + gemm1 (remaining blocks)
  front_k<<<NBLK + gemmGrid, 256, 0, stream>>>(x, W1, W2, w2s, xw, N,
                                               ei, counts, E, NBLK, NB1, NBUCK);

  scanR_k<<<NBUCK, 256, 0, stream>>>(counts, NBLK, NB1);
  partition_k<<<NBLK, 256, 0, stream>>>(counts, ei, ebuf, E, NBLK, NB1, NBUCK);
  build_k<<<NBUCK, BLD_T, 0, stream>>>(ebuf, counts, row_ptr, csr,
                                       N, E, NBLK, NB1, NBUCK);

  agg1g2_k<<<aggGrid1, 256, 0, stream>>>(xw, row_ptr, csr, b1, w2s, W2, hw, N);
  agg2_ls_k<<<aggGrid2, 256, 0, stream>>>(hw, row_ptr, csr, b2, out, N);
}